// Round 9
// baseline (1004.224 us; speedup 1.0000x reference)
//
#include <hip/hip_runtime.h>

typedef __bf16 bf16x8 __attribute__((ext_vector_type(8)));
typedef float f32x4 __attribute__((ext_vector_type(4)));
typedef unsigned short u16x8 __attribute__((ext_vector_type(8)));

#define B_SZ 2
#define T_SEQ 2048
#define D_MODEL 2048
#define N_HEADS 16
#define D_HEAD 128
#define D_FF 8192
#define BT (B_SZ * T_SEQ)
#define NT (T_SEQ / 64)

__device__ __forceinline__ unsigned short f2bf(float f) {
  unsigned int u = __builtin_bit_cast(unsigned int, f);
  u += 0x7FFFu + ((u >> 16) & 1u);
  return (unsigned short)(u >> 16);
}
__device__ __forceinline__ float bf2f(unsigned short h) {
  unsigned int u = ((unsigned int)h) << 16;
  return __builtin_bit_cast(float, u);
}

__device__ __forceinline__ void load_lds16(const void* g, void* l) {
  __builtin_amdgcn_global_load_lds(
      (const __attribute__((address_space(1))) unsigned int*)g,
      (__attribute__((address_space(3))) unsigned int*)l, 16, 0, 0);
}

// ---------------- transpose + cast: in fp32 [R][C] -> out bf16 [C][R] -------
__global__ __launch_bounds__(256) void transpose_cast_kernel(
    const float* __restrict__ in, unsigned short* __restrict__ out, int R, int C) {
  __shared__ float tile[32][33];
  const int tx = threadIdx.x, ty = threadIdx.y;
  const int c0 = blockIdx.x * 32, r0 = blockIdx.y * 32;
#pragma unroll
  for (int i = 0; i < 4; ++i)
    tile[ty + 8 * i][tx] = in[(long)(r0 + ty + 8 * i) * C + c0 + tx];
  __syncthreads();
#pragma unroll
  for (int i = 0; i < 4; ++i)
    out[(long)(c0 + ty + 8 * i) * R + r0 + tx] = f2bf(tile[tx][ty + 8 * i]);
}

// ---------------- RMSNorm fp32 row -> bf16 ----------------------------------
__global__ __launch_bounds__(256) void rmsnorm_cast_kernel(
    const float* __restrict__ x, const float* __restrict__ gw,
    unsigned short* __restrict__ out) {
  const int row = blockIdx.x;
  const int tid = threadIdx.x;
  const float* xr = x + (long)row * D_MODEL;
  float4 a = *(const float4*)(xr + tid * 8);
  float4 b = *(const float4*)(xr + tid * 8 + 4);
  float ss = a.x * a.x + a.y * a.y + a.z * a.z + a.w * a.w +
             b.x * b.x + b.y * b.y + b.z * b.z + b.w * b.w;
#pragma unroll
  for (int d = 1; d < 64; d <<= 1) ss += __shfl_xor(ss, d);
  __shared__ float part[4];
  if ((tid & 63) == 0) part[tid >> 6] = ss;
  __syncthreads();
  ss = part[0] + part[1] + part[2] + part[3];
  const float rs = rsqrtf(ss * (1.0f / D_MODEL) + 1e-6f);
  float4 g0 = *(const float4*)(gw + tid * 8);
  float4 g1 = *(const float4*)(gw + tid * 8 + 4);
  ushort4 o0, o1;
  o0.x = f2bf(a.x * rs * g0.x); o0.y = f2bf(a.y * rs * g0.y);
  o0.z = f2bf(a.z * rs * g0.z); o0.w = f2bf(a.w * rs * g0.w);
  o1.x = f2bf(b.x * rs * g1.x); o1.y = f2bf(b.y * rs * g1.y);
  o1.z = f2bf(b.z * rs * g1.z); o1.w = f2bf(b.w * rs * g1.w);
  unsigned short* op = out + (long)row * D_MODEL + tid * 8;
  *(ushort4*)op = o0;
  *(ushort4*)(op + 4) = o1;
}

// ---------------- 8-phase-style GEMM: 256x128 tile, BK=64, 3-tile ring ------
// C[M,N] = A[M,K] @ Bt[N,K]^T. 512 thr = 8 waves (4M x 2N), per-wave 64x64
// (acc[4][4] = 64 regs -> frag headroom under the 256-reg 2-wave/SIMD cap).
// LDS: 3 K-tile bufs x (A 32KB + B 16KB) = 144 KiB (1 block/CU -> all overlap
// must be intra-block; hence the per-phase interleave below, per m196/m201).
// Per K-tile window = 4 phases, each:
//   {ds_read 4-8 b128 | issue 1-2 global_load_lds of tile kt+2}
//   sched_barrier; s_barrier; lgkmcnt(0); sched_barrier;        (rule 18)
//   setprio(1); 8 MFMA; setprio(0); s_barrier
// One counted vmcnt(6) gate per window (never 0 mid-loop): after the gate the
// only outstanding loads are this window's 6 (tile kt+2), so tile kt+1 has
// provably landed. Ring safety: tile kt+2 writes buf (kt+2)%3 whose tenant
// kt-1 finished its last ds_read at window kt-1's final barrier.
// LDS layout per tile: [rows][8 x 16B-slot], slot u ^= (row&7) — r7-measured
// ZERO bank conflicts for this exact ds_read pattern; staged with the inverse
// swizzle on the global source (linear LDS dest, rule 21).
template <int EPI>
__global__ __launch_bounds__(512, 1) void gemm8p_kernel(
    const unsigned short* __restrict__ A, const unsigned short* __restrict__ Bt,
    void* __restrict__ Cout, const void* __restrict__ aux,
    int M, int N, int K, int lda, int ldb, int ldc, int cm, int cn) {
  constexpr int ASZ = 256 * 64;
  constexpr int BSZ = 128 * 64;
  __shared__ unsigned short As[3 * ASZ];  // 96 KiB
  __shared__ unsigned short Bs[3 * BSZ];  // 48 KiB
  const int tid = threadIdx.x;
  const int lane = tid & 63, g = lane >> 4, c = lane & 15;
  const int w = tid >> 6, wr = w >> 1, wc = w & 1;
  const int c7 = c & 7;

  // rect XCD chunking: bid&7 = XCD owns cm x cn tile rectangle
  const int nbn = N >> 7;
  const int bid = (int)blockIdx.x;
  const int xcd = bid & 7, bidx = bid >> 3;
  const int chn = nbn / cn;
  const int crow = xcd / chn, ccol = xcd % chn;
  const int m0 = (crow * cm + bidx / cn) << 8;
  const int n0 = (ccol * cn + bidx % cn) << 7;

  const int nkt = K >> 6;
  const unsigned short* A_ = A + (long)m0 * lda;
  const unsigned short* B_ = Bt + (long)n0 * ldb;

  auto stgA = [&](int sb, int kt2, int j) {
    const int idx = j * 512 + tid;
    const int row = idx >> 3;
    const int u = (idx & 7) ^ (row & 7);
    load_lds16(A_ + (long)row * lda + (long)kt2 * 64 + u * 8, &As[sb * ASZ + idx * 8]);
  };
  auto stgB = [&](int sb, int kt2, int j) {
    const int idx = j * 512 + tid;
    const int row = idx >> 3;
    const int u = (idx & 7) ^ (row & 7);
    load_lds16(B_ + (long)row * ldb + (long)kt2 * 64 + u * 8, &Bs[sb * BSZ + idx * 8]);
  };

  f32x4 acc[4][4] = {};

  // prologue: stage tiles 0 and 1 (6 loads each); retire tile 0 via vmcnt(6)
  stgA(0, 0, 0); stgA(0, 0, 1); stgA(0, 0, 2); stgA(0, 0, 3);
  stgB(0, 0, 0); stgB(0, 0, 1);
  stgA(1, 1, 0); stgA(1, 1, 1); stgA(1, 1, 2); stgA(1, 1, 3);
  stgB(1, 1, 0); stgB(1, 1, 1);
  asm volatile("s_waitcnt vmcnt(6)" ::: "memory");
  __builtin_amdgcn_sched_barrier(0);
  __builtin_amdgcn_s_barrier();

  for (int kt = 0; kt < nkt; ++kt) {
    const int rb = kt % 3;
    const int sb = (kt + 2) % 3;
    const bool st = (kt + 2) < nkt;
    const unsigned short* Ab = &As[rb * ASZ] + (wr * 64) * 64;
    const unsigned short* Bb = &Bs[rb * BSZ] + (wc * 64) * 64;
    bf16x8 fa0[4], fa1[4], fb0[4], fb1[4];

    // ---- phase 0: read ks0 fa+fb (8 b128); stage A j0,j1; MFMA ks0 fn0,1 --
#pragma unroll
    for (int i = 0; i < 4; ++i) {
      fa0[i] = *(const bf16x8*)(Ab + (i * 16 + c) * 64 + ((g ^ c7) * 8));
      fb0[i] = *(const bf16x8*)(Bb + (i * 16 + c) * 64 + ((g ^ c7) * 8));
    }
    if (st) { stgA(sb, kt + 2, 0); stgA(sb, kt + 2, 1); }
    __builtin_amdgcn_sched_barrier(0);
    __builtin_amdgcn_s_barrier();
    asm volatile("s_waitcnt lgkmcnt(0)" ::: "memory");
    __builtin_amdgcn_sched_barrier(0);
    __builtin_amdgcn_s_setprio(1);
#pragma unroll
    for (int fm = 0; fm < 4; ++fm) {
      acc[fm][0] = __builtin_amdgcn_mfma_f32_16x16x32_bf16(fa0[fm], fb0[0], acc[fm][0], 0, 0, 0);
      acc[fm][1] = __builtin_amdgcn_mfma_f32_16x16x32_bf16(fa0[fm], fb0[1], acc[fm][1], 0, 0, 0);
    }
    __builtin_amdgcn_s_setprio(0);
    __builtin_amdgcn_s_barrier();

    // ---- phase 1: read ks1 fa (4 b128); stage A j2,j3; MFMA ks0 fn2,3 -----
#pragma unroll
    for (int i = 0; i < 4; ++i)
      fa1[i] = *(const bf16x8*)(Ab + (i * 16 + c) * 64 + (((4 + g) ^ c7) * 8));
    if (st) { stgA(sb, kt + 2, 2); stgA(sb, kt + 2, 3); }
    __builtin_amdgcn_sched_barrier(0);
    __builtin_amdgcn_s_barrier();
    asm volatile("s_waitcnt lgkmcnt(0)" ::: "memory");
    __builtin_amdgcn_sched_barrier(0);
    __builtin_amdgcn_s_setprio(1);
#pragma unroll
    for (int fm = 0; fm < 4; ++fm) {
      acc[fm][2] = __builtin_amdgcn_mfma_f32_16x16x32_bf16(fa0[fm], fb0[2], acc[fm][2], 0, 0, 0);
      acc[fm][3] = __builtin_amdgcn_mfma_f32_16x16x32_bf16(fa0[fm], fb0[3], acc[fm][3], 0, 0, 0);
    }
    __builtin_amdgcn_s_setprio(0);
    __builtin_amdgcn_s_barrier();

    // ---- phase 2: read ks1 fb (4 b128); stage B j0; MFMA ks1 fn0,1 --------
#pragma unroll
    for (int i = 0; i < 4; ++i)
      fb1[i] = *(const bf16x8*)(Bb + (i * 16 + c) * 64 + (((4 + g) ^ c7) * 8));
    if (st) stgB(sb, kt + 2, 0);
    __builtin_amdgcn_sched_barrier(0);
    __builtin_amdgcn_s_barrier();
    asm volatile("s_waitcnt lgkmcnt(0)" ::: "memory");
    __builtin_amdgcn_sched_barrier(0);
    __builtin_amdgcn_s_setprio(1);
#pragma unroll
    for (int fm = 0; fm < 4; ++fm) {
      acc[fm][0] = __builtin_amdgcn_mfma_f32_16x16x32_bf16(fa1[fm], fb1[0], acc[fm][0], 0, 0, 0);
      acc[fm][1] = __builtin_amdgcn_mfma_f32_16x16x32_bf16(fa1[fm], fb1[1], acc[fm][1], 0, 0, 0);
    }
    __builtin_amdgcn_s_setprio(0);
    __builtin_amdgcn_s_barrier();

    // ---- phase 3: stage B j1; MFMA ks1 fn2,3; counted gate ----------------
    if (st) stgB(sb, kt + 2, 1);
    __builtin_amdgcn_sched_barrier(0);
    __builtin_amdgcn_s_barrier();
    __builtin_amdgcn_s_setprio(1);
#pragma unroll
    for (int fm = 0; fm < 4; ++fm) {
      acc[fm][2] = __builtin_amdgcn_mfma_f32_16x16x32_bf16(fa1[fm], fb1[2], acc[fm][2], 0, 0, 0);
      acc[fm][3] = __builtin_amdgcn_mfma_f32_16x16x32_bf16(fa1[fm], fb1[3], acc[fm][3], 0, 0, 0);
    }
    __builtin_amdgcn_s_setprio(0);
    if (kt + 1 == nkt) break;
    if (st)
      asm volatile("s_waitcnt vmcnt(6)" ::: "memory");  // tile kt+1 landed
    else
      asm volatile("s_waitcnt vmcnt(0)" ::: "memory");
    __builtin_amdgcn_sched_barrier(0);
    __builtin_amdgcn_s_barrier();
  }

#pragma unroll
  for (int fm = 0; fm < 4; ++fm) {
#pragma unroll
    for (int r = 0; r < 4; ++r) {
      const int row = m0 + wr * 64 + fm * 16 + 4 * g + r;
#pragma unroll
      for (int fn = 0; fn < 4; ++fn) {
        const int col = n0 + wc * 64 + fn * 16 + c;
        const long idx = (long)row * ldc + col;
        float v = acc[fm][fn][r];
        if constexpr (EPI == 0) {
          ((unsigned short*)Cout)[idx] = f2bf(v);
        } else if constexpr (EPI == 1) {
          ((float*)Cout)[idx] = v + ((const float*)aux)[idx];
        } else {
          const float u = bf2f(((const unsigned short*)aux)[idx]);
          const float s = v / (1.0f + __expf(-v));
          ((unsigned short*)Cout)[idx] = f2bf(s * u);
        }
      }
    }
  }
}

// ---------------- RoPE tables -----------------------------------------------
__global__ void rope_tables_kernel(float* __restrict__ cost, float* __restrict__ sint) {
  const int idx = blockIdx.x * 256 + threadIdx.x;  // T*64
  const int t = idx >> 6, i = idx & 63;
  const float invf = powf(10000.0f, -(float)i * (1.0f / 64.0f));
  const float ang = (float)t * invf;
  cost[idx] = cosf(ang);
  sint[idx] = sinf(ang);
}

// ---------------- RoPE apply in-place on q,k halves of qkv(bf16) ------------
__global__ __launch_bounds__(256) void rope_apply_kernel(
    unsigned short* __restrict__ qkv, const float* __restrict__ cost,
    const float* __restrict__ sint) {
  const long idx = (long)blockIdx.x * 256 + threadIdx.x;  // BT*16*64*2
  const int i = idx & 63;
  const int h = (idx >> 6) & 15;
  const int qk = (idx >> 10) & 1;
  const int row = idx >> 11;          // 0..BT-1
  const int t = row & (T_SEQ - 1);
  unsigned short* p = qkv + (long)row * (3 * D_MODEL) + qk * D_MODEL + h * D_HEAD + i;
  const float a = bf2f(p[0]);
  const float b = bf2f(p[64]);
  const float cv = cost[t * 64 + i];
  const float sv = sint[t * 64 + i];
  p[0] = f2bf(a * cv - b * sv);
  p[64] = f2bf(b * cv + a * sv);
}

// ---------------- V transpose: qkv v-part -> vt [B,H,128,T] bf16 ------------
__global__ __launch_bounds__(256) void vtrans_kernel(
    const unsigned short* __restrict__ qkv, unsigned short* __restrict__ vt) {
  __shared__ unsigned short tile[32][33];
  const int tx = threadIdx.x, ty = threadIdx.y;
  const int t0 = blockIdx.x * 32, d0 = blockIdx.y * 32;
  const int bh = blockIdx.z;  // b*16+h
  const int b = bh >> 4, h = bh & 15;
#pragma unroll
  for (int i = 0; i < 4; ++i)
    tile[ty + 8 * i][tx] =
        qkv[(long)(b * T_SEQ + t0 + ty + 8 * i) * (3 * D_MODEL) + 2 * D_MODEL + h * D_HEAD + d0 + tx];
  __syncthreads();
#pragma unroll
  for (int i = 0; i < 4; ++i)
    vt[((long)bh * D_HEAD + d0 + ty + 8 * i) * T_SEQ + t0 + tx] = tile[tx][ty + 8 * i];
}

// ---------------- Flash attention (causal), swapped-QK^T --------------------
__global__ __launch_bounds__(256) void attn_kernel(
    const unsigned short* __restrict__ qkv, const unsigned short* __restrict__ vt,
    unsigned short* __restrict__ ctx) {
  __shared__ unsigned short Ks[2][64 * 128];
  __shared__ unsigned short Vs[2][128 * 64];
  const int h = blockIdx.y, b = blockIdx.z;
  const int tid = threadIdx.x;
  const int w = tid >> 6, lane = tid & 63, g = lane >> 4, c = lane & 15;
  const float scale = 0.08838834764831845f;  // 128^-0.5
  const int srcA = (2 * (g & 1)) * 16 + c;
  const int srcB = srcA + 16;
  const bool hi = (g >> 1) != 0;
  const int bh = b * N_HEADS + h;

  const int ssk = (tid & 15) ^ ((tid >> 4) & 7);
  const int ssv = (tid & 7) ^ ((tid >> 3) & 7);
  const unsigned short* Kg = qkv + (long)b * T_SEQ * 3 * D_MODEL + D_MODEL + (long)h * D_HEAD;
  const unsigned short* Vg = vt + (long)bh * D_HEAD * T_SEQ;

  auto stage = [&](int kv0, int bufi) {
#pragma unroll
    for (int i = 0; i < 4; ++i) {
      const int rowk = i * 16 + (tid >> 4);
      load_lds16(Kg + (long)(kv0 + rowk) * (3 * D_MODEL) + ssk * 8,
                 &Ks[bufi][(i * 256 + tid) * 8]);
    }
#pragma unroll
    for (int i = 0; i < 4; ++i) {
      const int rowv = i * 32 + (tid >> 3);
      load_lds16(Vg + (long)rowv * T_SEQ + kv0 + ssv * 8,
                 &Vs[bufi][(i * 256 + tid) * 8]);
    }
  };

  const int cs7 = c & 7;

  for (int pass = 0; pass < 2; ++pass) {
    const int qt = pass ? (NT - 1 - blockIdx.x) : blockIdx.x;
    const int q = qt * 64 + w * 16 + c;

    bf16x8 fq[4];
    const long rowQ = (long)(b * T_SEQ + q) * (3 * D_MODEL) + h * D_HEAD;
#pragma unroll
    for (int ks = 0; ks < 4; ++ks)
      fq[ks] = *(const bf16x8*)(qkv + rowQ + ks * 32 + g * 8);

    f32x4 o[8] = {};
    float mrun = -INFINITY, ell = 0.0f;

    stage(0, 0);
    asm volatile("s_waitcnt vmcnt(0)" ::: "memory");
    __syncthreads();
    int buf = 0;

    for (int kt = 0; kt <= qt; ++kt) {
      const int kv0 = kt * 64;
      if (kt < qt) stage(kv0 + 64, buf ^ 1);

      f32x4 s[4] = {};
#pragma unroll
      for (int fm = 0; fm < 4; ++fm) {
        const unsigned short* kr = &Ks[buf][(fm * 16 + c) * 128];
#pragma unroll
        for (int ks = 0; ks < 4; ++ks) {
          bf16x8 ak = *(const bf16x8*)(kr + ((ks * 4 + g) ^ cs7) * 8);
          s[fm] = __builtin_amdgcn_mfma_f32_16x16x32_bf16(ak, fq[ks], s[fm], 0, 0, 0);
        }
      }
      float pmax = -INFINITY;
      const bool diag = (kt == qt);
#pragma unroll
      for (int fm = 0; fm < 4; ++fm)
#pragma unroll
        for (int r = 0; r < 4; ++r) {
          float sv = s[fm][r] * scale;
          if (diag) {
            const int kp = kv0 + fm * 16 + 4 * g + r;
            if (kp > q) sv = -INFINITY;
          }
          s[fm][r] = sv;
          pmax = fmaxf(pmax, sv);
        }
      pmax = fmaxf(pmax, __shfl_xor(pmax, 16));
      pmax = fmaxf(pmax, __shfl_xor(pmax, 32));
      const float mnew = fmaxf(mrun, pmax);
      const float resc = __expf(mrun - mnew);
      mrun = mnew;
      float rowsum = 0.0f;
#pragma unroll
      for (int fm = 0; fm < 4; ++fm)
#pragma unroll
        for (int r = 0; r < 4; ++r) {
          const float p = __expf(s[fm][r] - mnew);
          s[fm][r] = p;
          rowsum += p;
        }
      rowsum += __shfl_xor(rowsum, 16);
      rowsum += __shfl_xor(rowsum, 32);
      ell = ell * resc + rowsum;
#pragma unroll
      for (int fm = 0; fm < 8; ++fm) o[fm] *= resc;

      bf16x8 pb[2];
#pragma unroll
      for (int k2 = 0; k2 < 2; ++k2) {
        float va[4], vb[4];
#pragma unroll
        for (int r = 0; r < 4; ++r) {
          const float t0 = __shfl(s[k2 * 2][r], srcA);
          const float t1 = __shfl(s[k2 * 2 + 1][r], srcA);
          va[r] = hi ? t1 : t0;
          const float u0 = __shfl(s[k2 * 2][r], srcB);
          const float u1 = __shfl(s[k2 * 2 + 1][r], srcB);
          vb[r] = hi ? u1 : u0;
        }
        bf16x8 pv;
        pv[0] = (__bf16)va[0]; pv[1] = (__bf16)va[1];
        pv[2] = (__bf16)va[2]; pv[3] = (__bf16)va[3];
        pv[4] = (__bf16)vb[0]; pv[5] = (__bf16)vb[1];
        pv[6] = (__bf16)vb[2]; pv[7] = (__bf16)vb[3];
        pb[k2] = pv;
      }
#pragma unroll
      for (int fm = 0; fm < 8; ++fm) {
        const unsigned short* vr = &Vs[buf][(fm * 16 + c) * 64];
#pragma unroll
        for (int k2 = 0; k2 < 2; ++k2) {
          bf16x8 av = *(const bf16x8*)(vr + ((k2 * 4 + g) ^ cs7) * 8);
          o[fm] = __builtin_amdgcn_mfma_f32_16x16x32_bf16(av, pb[k2], o[fm], 0, 0, 0);
        }
      }
      asm volatile("s_waitcnt vmcnt(0)" ::: "memory");
      __syncthreads();
      buf ^= 1;
    }

    const float inv = 1.0f / ell;
    unsigned short* outp = ctx + (long)(b * T_SEQ + q) * D_MODEL + h * D_HEAD;
#pragma unroll
    for (int fm = 0; fm < 8; ++fm) {
      ushort4 pk;
      pk.x = f2bf(o[fm][0] * inv);
      pk.y = f2bf(o[fm][1] * inv);
      pk.z = f2bf(o[fm][2] * inv);
      pk.w = f2bf(o[fm][3] * inv);
      *(ushort4*)(outp + fm * 16 + 4 * g) = pk;
    }
  }
}

// ---------------------------------------------------------------------------
extern "C" void kernel_launch(void* const* d_in, const int* in_sizes, int n_in,
                              void* d_out, int out_size, void* d_ws, size_t ws_size,
                              hipStream_t stream) {
  const float* x = (const float*)d_in[0];
  const float* w_qkv = (const float*)d_in[1];
  const float* w_out = (const float*)d_in[2];
  const float* g1 = (const float*)d_in[3];
  const float* g2 = (const float*)d_in[4];
  const float* w_g = (const float*)d_in[5];
  const float* w_u = (const float*)d_in[6];
  const float* w_o = (const float*)d_in[7];
  float* out = (float*)d_out;

  char* ws = (char*)d_ws;
  size_t off = 0;
  auto take = [&](size_t bytes) {
    char* p = ws + off;
    off += (bytes + 255) & ~(size_t)255;
    return p;
  };

  // weight region (phase A and phase B alias the same memory)
  char* Wreg = take((size_t)3 * D_FF * D_MODEL * 2);  // 100.66 MB
  unsigned short* wTqkv = (unsigned short*)Wreg;
  unsigned short* wTout = (unsigned short*)(Wreg + (size_t)3 * D_MODEL * D_MODEL * 2);
  unsigned short* wTg = (unsigned short*)Wreg;
  unsigned short* wTu = (unsigned short*)(Wreg + (size_t)D_FF * D_MODEL * 2);
  unsigned short* wTo = (unsigned short*)(Wreg + (size_t)2 * D_FF * D_MODEL * 2);

  // activation region (phase A and phase B alias the same memory)
  const size_t qkv_b = (size_t)BT * 3 * D_MODEL * 2;
  const size_t vt_b = (size_t)B_SZ * N_HEADS * D_HEAD * T_SEQ * 2;
  const size_t ctx_b = (size_t)BT * D_MODEL * 2;
  char* AR = take(qkv_b + vt_b + ctx_b);  // 83.9 MB
  unsigned short* qkvb = (unsigned short*)AR;
  unsigned short* vtb = (unsigned short*)(AR + qkv_b);
  unsigned short* ctxb = (unsigned short*)(AR + qkv_b + vt_b);
  unsigned short* gbuf = (unsigned short*)AR;                                  // 33.6 MB
  unsigned short* ubuf = (unsigned short*)(AR + (size_t)BT * (D_FF / 2) * 2);  // 33.6 MB

  float* x1 = (float*)take((size_t)BT * D_MODEL * 4);
  unsigned short* hb = (unsigned short*)take((size_t)BT * D_MODEL * 2);
  float* cost = (float*)take((size_t)T_SEQ * 64 * 4);
  float* sint = (float*)take((size_t)T_SEQ * 64 * 4);

  const dim3 tb(32, 8);

  // ---- phase A: attention ----
  transpose_cast_kernel<<<dim3(3 * D_MODEL / 32, D_MODEL / 32), tb, 0, stream>>>(w_qkv, wTqkv, D_MODEL, 3 * D_MODEL);
  transpose_cast_kernel<<<dim3(D_MODEL / 32, D_MODEL / 32), tb, 0, stream>>>(w_out, wTout, D_MODEL, D_MODEL);
  rope_tables_kernel<<<T_SEQ * 64 / 256, 256, 0, stream>>>(cost, sint);

  rmsnorm_cast_kernel<<<BT, 256, 0, stream>>>(x, g1, hb);
  // QKV: nbm=16, nbn=48 -> 768 blocks; XCD rect 8x12
  gemm8p_kernel<0><<<768, 512, 0, stream>>>(
      hb, wTqkv, qkvb, nullptr, BT, 3 * D_MODEL, D_MODEL, D_MODEL, D_MODEL, 3 * D_MODEL, 8, 12);
  rope_apply_kernel<<<(BT * N_HEADS * 64 * 2) / 256, 256, 0, stream>>>(qkvb, cost, sint);
  vtrans_kernel<<<dim3(T_SEQ / 32, D_HEAD / 32, B_SZ * N_HEADS), tb, 0, stream>>>(qkvb, vtb);
  attn_kernel<<<dim3(NT / 2, N_HEADS, B_SZ), 256, 0, stream>>>(qkvb, vtb, ctxb);
  // out-proj: nbm=16, nbn=16 -> 256 blocks; XCD rect 8x4
  gemm8p_kernel<1><<<256, 512, 0, stream>>>(
      ctxb, wTout, x1, x, BT, D_MODEL, D_MODEL, D_MODEL, D_MODEL, D_MODEL, 8, 4);

  // ---- phase B: MLP, N-halved (M=4096 everywhere) ----
  transpose_cast_kernel<<<dim3(D_FF / 32, D_MODEL / 32), tb, 0, stream>>>(w_g, wTg, D_MODEL, D_FF);
  transpose_cast_kernel<<<dim3(D_FF / 32, D_MODEL / 32), tb, 0, stream>>>(w_u, wTu, D_MODEL, D_FF);
  transpose_cast_kernel<<<dim3(D_MODEL / 32, D_FF / 32), tb, 0, stream>>>(w_o, wTo, D_FF, D_MODEL);
  rmsnorm_cast_kernel<<<BT, 256, 0, stream>>>(x1, g2, hb);

  const int NH = D_FF / 2;  // 4096 ff-columns per half
  for (int half = 0; half < 2; ++half) {
    const unsigned short* wTu_h = wTu + (size_t)half * NH * D_MODEL;
    const unsigned short* wTg_h = wTg + (size_t)half * NH * D_MODEL;
    const unsigned short* wTo_h = wTo + (size_t)half * NH;  // K-slice of [2048][8192]
    // up half: nbm=16, nbn=32 -> 512 blocks; XCD rect 8x8
    gemm8p_kernel<0><<<512, 512, 0, stream>>>(
        hb, wTu_h, ubuf, nullptr, BT, NH, D_MODEL, D_MODEL, D_MODEL, NH, 8, 8);
    // gate half + fused SwiGLU (reads ubuf)
    gemm8p_kernel<2><<<512, 512, 0, stream>>>(
        hb, wTg_h, gbuf, ubuf, BT, NH, D_MODEL, D_MODEL, D_MODEL, NH, 8, 8);
    // down half: nbm=16, nbn=16 -> 256 blocks; XCD rect 8x4 (K=4096)
    gemm8p_kernel<1><<<256, 512, 0, stream>>>(
        gbuf, wTo_h, out, (half == 0) ? x1 : out, BT, D_MODEL, NH, NH, D_FF, D_MODEL, 8, 4);
  }
}

// Round 10
// 843.654 us; speedup vs baseline: 1.1903x; 1.1903x over previous
//
#include <hip/hip_runtime.h>

typedef __bf16 bf16x8 __attribute__((ext_vector_type(8)));
typedef float f32x4 __attribute__((ext_vector_type(4)));
typedef unsigned short u16x8 __attribute__((ext_vector_type(8)));

#define B_SZ 2
#define T_SEQ 2048
#define D_MODEL 2048
#define N_HEADS 16
#define D_HEAD 128
#define D_FF 8192
#define BT (B_SZ * T_SEQ)
#define NT (T_SEQ / 64)

__device__ __forceinline__ unsigned short f2bf(float f) {
  unsigned int u = __builtin_bit_cast(unsigned int, f);
  u += 0x7FFFu + ((u >> 16) & 1u);
  return (unsigned short)(u >> 16);
}
__device__ __forceinline__ float bf2f(unsigned short h) {
  unsigned int u = ((unsigned int)h) << 16;
  return __builtin_bit_cast(float, u);
}

__device__ __forceinline__ void load_lds16(const void* g, void* l) {
  __builtin_amdgcn_global_load_lds(
      (const __attribute__((address_space(1))) unsigned int*)g,
      (__attribute__((address_space(3))) unsigned int*)l, 16, 0, 0);
}

// ---------------- transpose + cast: in fp32 [R][C] -> out bf16 [C][R] -------
__global__ __launch_bounds__(256) void transpose_cast_kernel(
    const float* __restrict__ in, unsigned short* __restrict__ out, int R, int C) {
  __shared__ float tile[32][33];
  const int tx = threadIdx.x, ty = threadIdx.y;
  const int c0 = blockIdx.x * 32, r0 = blockIdx.y * 32;
#pragma unroll
  for (int i = 0; i < 4; ++i)
    tile[ty + 8 * i][tx] = in[(long)(r0 + ty + 8 * i) * C + c0 + tx];
  __syncthreads();
#pragma unroll
  for (int i = 0; i < 4; ++i)
    out[(long)(c0 + ty + 8 * i) * R + r0 + tx] = f2bf(tile[tx][ty + 8 * i]);
}

// ---------------- RMSNorm fp32 row -> bf16 ----------------------------------
__global__ __launch_bounds__(256) void rmsnorm_cast_kernel(
    const float* __restrict__ x, const float* __restrict__ gw,
    unsigned short* __restrict__ out) {
  const int row = blockIdx.x;
  const int tid = threadIdx.x;
  const float* xr = x + (long)row * D_MODEL;
  float4 a = *(const float4*)(xr + tid * 8);
  float4 b = *(const float4*)(xr + tid * 8 + 4);
  float ss = a.x * a.x + a.y * a.y + a.z * a.z + a.w * a.w +
             b.x * b.x + b.y * b.y + b.z * b.z + b.w * b.w;
#pragma unroll
  for (int d = 1; d < 64; d <<= 1) ss += __shfl_xor(ss, d);
  __shared__ float part[4];
  if ((tid & 63) == 0) part[tid >> 6] = ss;
  __syncthreads();
  ss = part[0] + part[1] + part[2] + part[3];
  const float rs = rsqrtf(ss * (1.0f / D_MODEL) + 1e-6f);
  float4 g0 = *(const float4*)(gw + tid * 8);
  float4 g1 = *(const float4*)(gw + tid * 8 + 4);
  ushort4 o0, o1;
  o0.x = f2bf(a.x * rs * g0.x); o0.y = f2bf(a.y * rs * g0.y);
  o0.z = f2bf(a.z * rs * g0.z); o0.w = f2bf(a.w * rs * g0.w);
  o1.x = f2bf(b.x * rs * g1.x); o1.y = f2bf(b.y * rs * g1.y);
  o1.z = f2bf(b.z * rs * g1.z); o1.w = f2bf(b.w * rs * g1.w);
  unsigned short* op = out + (long)row * D_MODEL + tid * 8;
  *(ushort4*)op = o0;
  *(ushort4*)(op + 4) = o1;
}

// ---------------- m201-port GEMM: 256x256, BK=64, half-tile pipeline --------
// 512 thr = 8 waves (2M x 4N), per-wave 128x64 out (acc[8][4] = 128 regs).
// LDS: [2 buf][2 half(128 rows)][128x64] per matrix = 128 KiB total.
// Per K-tile: 4 phases, each {ds_read frags, stage ONE half (2 loads),
//   s_barrier, lgkmcnt(0)+sched_barrier, setprio(1), 16 MFMA, setprio(0),
//   s_barrier} -> 2 barriers per 16 MFMA (m201 ratio).
// Stage schedule for tile t: P0:B0(t+1) P1:A1(t+1) P2:B1(t+1) P3:A0(t+2).
// Slot-reuse ledger (all gaps >= 1 barrier):
//   B0(t-1) last read P1(t-1) frags ks1 @P3(t-1) -> staged @P0(t)  OK
//   A1(t-1) last read @P2(t-1)                    -> staged @P1(t)  OK
//   B1(t-1) last read @P3(t-1)                    -> staged @P2(t)  OK
//   A0(t)   last read @P2(t)                      -> staged @P3(t)  OK
// Gate: ONE vmcnt(2) per tile at P3 (t+1's 4 stages landed; t+2's A0 still
// in flight -> counted, never 0 mid-loop). Conflict-free XOR layout
// (u ^= row&7, r7-measured 0 conflicts), linear LDS dest + pre-swz source.
template <int EPI>
__global__ __launch_bounds__(512, 2) void gemm8_kernel(
    const unsigned short* __restrict__ A, const unsigned short* __restrict__ Bt,
    void* __restrict__ Cout, const void* __restrict__ aux,
    int M, int N, int K, int lda, int ldb, int ldc, int cm, int cn) {
  __shared__ unsigned short As[2][2][128 * 64];  // 64 KiB
  __shared__ unsigned short Bs[2][2][128 * 64];  // 64 KiB
  const int tid = threadIdx.x;
  const int lane = tid & 63, g = lane >> 4, c = lane & 15;
  const int w = tid >> 6, wr = w >> 2, wc = w & 3;
  const int c7 = c & 7;

  // rect XCD chunking: bid&7 = XCD owns cm x cn tile rectangle
  const int nbn = N >> 8;
  const int bid = (int)blockIdx.x;
  const int xcd = bid & 7, bidx = bid >> 3;
  const int chn = nbn / cn;
  const int crow = xcd / chn, ccol = xcd % chn;
  const int m0 = (crow * cm + bidx / cn) << 8;
  const int n0 = (ccol * cn + bidx % cn) << 8;

  const int nkt = K >> 6;
  const unsigned short* A_ = A + (long)m0 * lda;
  const unsigned short* B_ = Bt + (long)n0 * ldb;

  auto stgA = [&](int t, int half) {
    const unsigned short* src = A_ + (long)(half * 128) * lda + (long)t * 64;
#pragma unroll
    for (int j = 0; j < 2; ++j) {
      const int idx = j * 512 + tid;
      const int row = idx >> 3, u = (idx & 7) ^ (row & 7);
      load_lds16(src + (long)row * lda + u * 8, &As[t & 1][half][idx * 8]);
    }
  };
  auto stgB = [&](int t, int half) {
    const unsigned short* src = B_ + (long)(half * 128) * ldb + (long)t * 64;
#pragma unroll
    for (int j = 0; j < 2; ++j) {
      const int idx = j * 512 + tid;
      const int row = idx >> 3, u = (idx & 7) ^ (row & 7);
      load_lds16(src + (long)row * ldb + u * 8, &Bs[t & 1][half][idx * 8]);
    }
  };

  f32x4 acc[8][4] = {};

  // prologue: all of tile 0 (8 loads) + A0 of tile 1 (2) -> vmcnt(2)
  stgA(0, 0); stgB(0, 0); stgA(0, 1); stgB(0, 1);
  stgA(1, 0);
  asm volatile("s_waitcnt vmcnt(2)" ::: "memory");
  __builtin_amdgcn_sched_barrier(0);
  __builtin_amdgcn_s_barrier();

  for (int t = 0; t < nkt; ++t) {
    const int buf = t & 1;
    const unsigned short* Ap = &As[buf][wr][0];                 // my A-half
    const unsigned short* Bp = &Bs[buf][wc >> 1][(wc & 1) * 64 * 64];  // my 64 cols
    bf16x8 fa[8], fb[4];

    // ---- P0: read fa[ks0](8) + fb01[ks0](2); stage B0(t+1); 16 MFMA ------
#pragma unroll
    for (int i = 0; i < 8; ++i)
      fa[i] = *(const bf16x8*)(Ap + (i * 16 + c) * 64 + ((g ^ c7) * 8));
#pragma unroll
    for (int i = 0; i < 2; ++i)
      fb[i] = *(const bf16x8*)(Bp + (i * 16 + c) * 64 + ((g ^ c7) * 8));
    if (t + 1 < nkt) stgB(t + 1, 0);
    __builtin_amdgcn_s_barrier();
    asm volatile("s_waitcnt lgkmcnt(0)" ::: "memory");
    __builtin_amdgcn_sched_barrier(0);
    __builtin_amdgcn_s_setprio(1);
#pragma unroll
    for (int fm = 0; fm < 8; ++fm) {
      acc[fm][0] = __builtin_amdgcn_mfma_f32_16x16x32_bf16(fa[fm], fb[0], acc[fm][0], 0, 0, 0);
      acc[fm][1] = __builtin_amdgcn_mfma_f32_16x16x32_bf16(fa[fm], fb[1], acc[fm][1], 0, 0, 0);
    }
    __builtin_amdgcn_s_setprio(0);
    __builtin_amdgcn_s_barrier();

    // ---- P1: read fb23[ks0](2); stage A1(t+1); 16 MFMA -------------------
#pragma unroll
    for (int i = 2; i < 4; ++i)
      fb[i] = *(const bf16x8*)(Bp + (i * 16 + c) * 64 + ((g ^ c7) * 8));
    if (t + 1 < nkt) stgA(t + 1, 1);
    __builtin_amdgcn_s_barrier();
    asm volatile("s_waitcnt lgkmcnt(0)" ::: "memory");
    __builtin_amdgcn_sched_barrier(0);
    __builtin_amdgcn_s_setprio(1);
#pragma unroll
    for (int fm = 0; fm < 8; ++fm) {
      acc[fm][2] = __builtin_amdgcn_mfma_f32_16x16x32_bf16(fa[fm], fb[2], acc[fm][2], 0, 0, 0);
      acc[fm][3] = __builtin_amdgcn_mfma_f32_16x16x32_bf16(fa[fm], fb[3], acc[fm][3], 0, 0, 0);
    }
    __builtin_amdgcn_s_setprio(0);
    __builtin_amdgcn_s_barrier();

    // ---- P2: read fa[ks1](8) + fb01[ks1](2); stage B1(t+1); 16 MFMA ------
#pragma unroll
    for (int i = 0; i < 8; ++i)
      fa[i] = *(const bf16x8*)(Ap + (i * 16 + c) * 64 + (((4 + g) ^ c7) * 8));
#pragma unroll
    for (int i = 0; i < 2; ++i)
      fb[i] = *(const bf16x8*)(Bp + (i * 16 + c) * 64 + (((4 + g) ^ c7) * 8));
    if (t + 1 < nkt) stgB(t + 1, 1);
    __builtin_amdgcn_s_barrier();
    asm volatile("s_waitcnt lgkmcnt(0)" ::: "memory");
    __builtin_amdgcn_sched_barrier(0);
    __builtin_amdgcn_s_setprio(1);
#pragma unroll
    for (int fm = 0; fm < 8; ++fm) {
      acc[fm][0] = __builtin_amdgcn_mfma_f32_16x16x32_bf16(fa[fm], fb[0], acc[fm][0], 0, 0, 0);
      acc[fm][1] = __builtin_amdgcn_mfma_f32_16x16x32_bf16(fa[fm], fb[1], acc[fm][1], 0, 0, 0);
    }
    __builtin_amdgcn_s_setprio(0);
    __builtin_amdgcn_s_barrier();

    // ---- P3: read fb23[ks1](2); stage A0(t+2); 16 MFMA; vmcnt gate -------
#pragma unroll
    for (int i = 2; i < 4; ++i)
      fb[i] = *(const bf16x8*)(Bp + (i * 16 + c) * 64 + (((4 + g) ^ c7) * 8));
    if (t + 2 < nkt) stgA(t + 2, 0);
    __builtin_amdgcn_s_barrier();
    asm volatile("s_waitcnt lgkmcnt(0)" ::: "memory");
    __builtin_amdgcn_sched_barrier(0);
    __builtin_amdgcn_s_setprio(1);
#pragma unroll
    for (int fm = 0; fm < 8; ++fm) {
      acc[fm][2] = __builtin_amdgcn_mfma_f32_16x16x32_bf16(fa[fm], fb[2], acc[fm][2], 0, 0, 0);
      acc[fm][3] = __builtin_amdgcn_mfma_f32_16x16x32_bf16(fa[fm], fb[3], acc[fm][3], 0, 0, 0);
    }
    __builtin_amdgcn_s_setprio(0);
    if (t + 1 == nkt) break;
    if (t + 2 < nkt)
      asm volatile("s_waitcnt vmcnt(2)" ::: "memory");  // t+1 landed, t+2 flying
    else
      asm volatile("s_waitcnt vmcnt(0)" ::: "memory");  // tail
    __builtin_amdgcn_sched_barrier(0);
    __builtin_amdgcn_s_barrier();
  }

#pragma unroll
  for (int fm = 0; fm < 8; ++fm) {
#pragma unroll
    for (int r = 0; r < 4; ++r) {
      const int row = m0 + wr * 128 + fm * 16 + 4 * g + r;
#pragma unroll
      for (int fn = 0; fn < 4; ++fn) {
        const int col = n0 + wc * 64 + fn * 16 + c;
        const long idx = (long)row * ldc + col;
        float v = acc[fm][fn][r];
        if constexpr (EPI == 0) {
          ((unsigned short*)Cout)[idx] = f2bf(v);
        } else if constexpr (EPI == 1) {
          ((float*)Cout)[idx] = v + ((const float*)aux)[idx];
        } else {
          const float u = bf2f(((const unsigned short*)aux)[idx]);
          const float s = v / (1.0f + __expf(-v));
          ((unsigned short*)Cout)[idx] = f2bf(s * u);
        }
      }
    }
  }
}

// ---------------- k-slice-ring 128x128 GEMM (N=2048 outputs) ----------------
template <int EPI, int WM, int WN, int FM, int FN>
__global__ __launch_bounds__(WM * WN * 64, 2) void gemm_ks_kernel(
    const unsigned short* __restrict__ A, const unsigned short* __restrict__ Bt,
    void* __restrict__ Cout, const void* __restrict__ aux,
    int M, int N, int K, int lda, int ldb, int ldc, int cm, int cn) {
  constexpr int THREADS = WM * WN * 64;
  constexpr int BM = WM * FM * 16;
  constexpr int BN = WN * FN * 16;
  constexpr int ASLOT = BM * 32;
  constexpr int BSLOT = BN * 32;
  constexpr int RPR = THREADS / 4;
  __shared__ unsigned short As[4 * ASLOT];
  __shared__ unsigned short Bs[4 * BSLOT];

  const int tid = threadIdx.x;
  const int lane = tid & 63, g = lane >> 4, c = lane & 15;
  const int w = tid >> 6, wr = w / WN, wc = w % WN;

  const int nbn = N / BN;
  const int bid = (int)blockIdx.x;
  const int xcd = bid & 7, idx = bid >> 3;
  const int chn = nbn / cn;
  const int crow = xcd / chn, ccol = xcd % chn;
  const int mr = idx / cn, nc2 = idx % cn;
  const int m0 = (crow * cm + mr) * BM;
  const int n0 = (ccol * cn + nc2) * BN;

  const int nks = K >> 5;
  const int srow = tid >> 2;
  const int kq8 = (tid & 3) * 8;
  const unsigned short* A_ = A + (long)m0 * lda;
  const unsigned short* B_ = Bt + (long)n0 * ldb;

  auto stage = [&](int s) {
    const int slot = s & 3;
    const long kofs = (long)s * 32 + kq8;
#pragma unroll
    for (int j = 0; j < BM / RPR; ++j)
      load_lds16(A_ + (long)(j * RPR + srow) * lda + kofs,
                 &As[slot * ASLOT + (j * THREADS + tid) * 8]);
#pragma unroll
    for (int j = 0; j < BN / RPR; ++j)
      load_lds16(B_ + (long)(j * RPR + srow) * ldb + kofs,
                 &Bs[slot * BSLOT + (j * THREADS + tid) * 8]);
  };

  f32x4 acc[FM][FN] = {};

  stage(0);
  if (nks > 1) stage(1);
  if (nks > 2) stage(2);
  asm volatile("s_waitcnt vmcnt(8)" ::: "memory");
  __builtin_amdgcn_sched_barrier(0);
  __builtin_amdgcn_s_barrier();

  for (int s = 0; s < nks; ++s) {
    const int slot = s & 3;
    const unsigned short* Ap = &As[slot * ASLOT] + (wr * FM * 16 + c) * 32 + g * 8;
    const unsigned short* Bp = &Bs[slot * BSLOT] + (wc * FN * 16 + c) * 32 + g * 8;
    bf16x8 fa[FM], fb[FN];
#pragma unroll
    for (int fm = 0; fm < FM; ++fm) fa[fm] = *(const bf16x8*)(Ap + fm * 512);
#pragma unroll
    for (int fn = 0; fn < FN; ++fn) fb[fn] = *(const bf16x8*)(Bp + fn * 512);
    if (s + 3 < nks) stage(s + 3);
    __builtin_amdgcn_s_setprio(1);
#pragma unroll
    for (int fm = 0; fm < FM; ++fm)
#pragma unroll
      for (int fn = 0; fn < FN; ++fn)
        acc[fm][fn] = __builtin_amdgcn_mfma_f32_16x16x32_bf16(fa[fm], fb[fn], acc[fm][fn], 0, 0, 0);
    __builtin_amdgcn_s_setprio(0);
    if (s + 1 == nks) break;
    if (s <= nks - 4)
      asm volatile("s_waitcnt vmcnt(8)" ::: "memory");
    else if (s == nks - 3)
      asm volatile("s_waitcnt vmcnt(4)" ::: "memory");
    else
      asm volatile("s_waitcnt vmcnt(0)" ::: "memory");
    __builtin_amdgcn_sched_barrier(0);
    __builtin_amdgcn_s_barrier();
  }

#pragma unroll
  for (int fm = 0; fm < FM; ++fm) {
#pragma unroll
    for (int r = 0; r < 4; ++r) {
      const int row = m0 + wr * FM * 16 + fm * 16 + 4 * g + r;
#pragma unroll
      for (int fn = 0; fn < FN; ++fn) {
        const int col = n0 + wc * FN * 16 + fn * 16 + c;
        const long idx2 = (long)row * ldc + col;
        float v = acc[fm][fn][r];
        if constexpr (EPI == 0) {
          ((unsigned short*)Cout)[idx2] = f2bf(v);
        } else if constexpr (EPI == 1) {
          ((float*)Cout)[idx2] = v + ((const float*)aux)[idx2];
        } else {
          const float u = bf2f(((const unsigned short*)aux)[idx2]);
          const float sg = v / (1.0f + __expf(-v));
          ((unsigned short*)Cout)[idx2] = f2bf(sg * u);
        }
      }
    }
  }
}

// ---------------- RoPE tables -----------------------------------------------
__global__ void rope_tables_kernel(float* __restrict__ cost, float* __restrict__ sint) {
  const int idx = blockIdx.x * 256 + threadIdx.x;  // T*64
  const int t = idx >> 6, i = idx & 63;
  const float invf = powf(10000.0f, -(float)i * (1.0f / 64.0f));
  const float ang = (float)t * invf;
  cost[idx] = cosf(ang);
  sint[idx] = sinf(ang);
}

// ---------------- RoPE apply in-place on q,k halves of qkv(bf16) ------------
__global__ __launch_bounds__(256) void rope_apply_kernel(
    unsigned short* __restrict__ qkv, const float* __restrict__ cost,
    const float* __restrict__ sint) {
  const long idx = (long)blockIdx.x * 256 + threadIdx.x;  // BT*16*64*2
  const int i = idx & 63;
  const int h = (idx >> 6) & 15;
  const int qk = (idx >> 10) & 1;
  const int row = idx >> 11;          // 0..BT-1
  const int t = row & (T_SEQ - 1);
  unsigned short* p = qkv + (long)row * (3 * D_MODEL) + qk * D_MODEL + h * D_HEAD + i;
  const float a = bf2f(p[0]);
  const float b = bf2f(p[64]);
  const float cv = cost[t * 64 + i];
  const float sv = sint[t * 64 + i];
  p[0] = f2bf(a * cv - b * sv);
  p[64] = f2bf(b * cv + a * sv);
}

// ---------------- V transpose: qkv v-part -> vt [B,H,128,T] bf16 ------------
__global__ __launch_bounds__(256) void vtrans_kernel(
    const unsigned short* __restrict__ qkv, unsigned short* __restrict__ vt) {
  __shared__ unsigned short tile[32][33];
  const int tx = threadIdx.x, ty = threadIdx.y;
  const int t0 = blockIdx.x * 32, d0 = blockIdx.y * 32;
  const int bh = blockIdx.z;  // b*16+h
  const int b = bh >> 4, h = bh & 15;
#pragma unroll
  for (int i = 0; i < 4; ++i)
    tile[ty + 8 * i][tx] =
        qkv[(long)(b * T_SEQ + t0 + ty + 8 * i) * (3 * D_MODEL) + 2 * D_MODEL + h * D_HEAD + d0 + tx];
  __syncthreads();
#pragma unroll
  for (int i = 0; i < 4; ++i)
    vt[((long)bh * D_HEAD + d0 + ty + 8 * i) * T_SEQ + t0 + tx] = tile[tx][ty + 8 * i];
}

// ---------------- Flash attention (causal), swapped-QK^T --------------------
__global__ __launch_bounds__(256) void attn_kernel(
    const unsigned short* __restrict__ qkv, const unsigned short* __restrict__ vt,
    unsigned short* __restrict__ ctx) {
  __shared__ unsigned short Ks[2][64 * 128];
  __shared__ unsigned short Vs[2][128 * 64];
  const int h = blockIdx.y, b = blockIdx.z;
  const int tid = threadIdx.x;
  const int w = tid >> 6, lane = tid & 63, g = lane >> 4, c = lane & 15;
  const float scale = 0.08838834764831845f;  // 128^-0.5
  const int srcA = (2 * (g & 1)) * 16 + c;
  const int srcB = srcA + 16;
  const bool hi = (g >> 1) != 0;
  const int bh = b * N_HEADS + h;

  const int ssk = (tid & 15) ^ ((tid >> 4) & 7);
  const int ssv = (tid & 7) ^ ((tid >> 3) & 7);
  const unsigned short* Kg = qkv + (long)b * T_SEQ * 3 * D_MODEL + D_MODEL + (long)h * D_HEAD;
  const unsigned short* Vg = vt + (long)bh * D_HEAD * T_SEQ;

  auto stage = [&](int kv0, int bufi) {
#pragma unroll
    for (int i = 0; i < 4; ++i) {
      const int rowk = i * 16 + (tid >> 4);
      load_lds16(Kg + (long)(kv0 + rowk) * (3 * D_MODEL) + ssk * 8,
                 &Ks[bufi][(i * 256 + tid) * 8]);
    }
#pragma unroll
    for (int i = 0; i < 4; ++i) {
      const int rowv = i * 32 + (tid >> 3);
      load_lds16(Vg + (long)rowv * T_SEQ + kv0 + ssv * 8,
                 &Vs[bufi][(i * 256 + tid) * 8]);
    }
  };

  const int cs7 = c & 7;

  for (int pass = 0; pass < 2; ++pass) {
    const int qt = pass ? (NT - 1 - blockIdx.x) : blockIdx.x;
    const int q = qt * 64 + w * 16 + c;

    bf16x8 fq[4];
    const long rowQ = (long)(b * T_SEQ + q) * (3 * D_MODEL) + h * D_HEAD;
#pragma unroll
    for (int ks = 0; ks < 4; ++ks)
      fq[ks] = *(const bf16x8*)(qkv + rowQ + ks * 32 + g * 8);

    f32x4 o[8] = {};
    float mrun = -INFINITY, ell = 0.0f;

    stage(0, 0);
    asm volatile("s_waitcnt vmcnt(0)" ::: "memory");
    __syncthreads();
    int buf = 0;

    for (int kt = 0; kt <= qt; ++kt) {
      const int kv0 = kt * 64;
      if (kt < qt) stage(kv0 + 64, buf ^ 1);

      f32x4 s[4] = {};
#pragma unroll
      for (int fm = 0; fm < 4; ++fm) {
        const unsigned short* kr = &Ks[buf][(fm * 16 + c) * 128];
#pragma unroll
        for (int ks = 0; ks < 4; ++ks) {
          bf16x8 ak = *(const bf16x8*)(kr + ((ks * 4 + g) ^ cs7) * 8);
          s[fm] = __builtin_amdgcn_mfma_f32_16x16x32_bf16(ak, fq[ks], s[fm], 0, 0, 0);
        }
      }
      float pmax = -INFINITY;
      const bool diag = (kt == qt);
#pragma unroll
      for (int fm = 0; fm < 4; ++fm)
#pragma unroll
        for (int r = 0; r < 4; ++r) {
          float sv = s[fm][r] * scale;
          if (diag) {
            const int kp = kv0 + fm * 16 + 4 * g + r;
            if (kp > q) sv = -INFINITY;
          }
          s[fm][r] = sv;
          pmax = fmaxf(pmax, sv);
        }
      pmax = fmaxf(pmax, __shfl_xor(pmax, 16));
      pmax = fmaxf(pmax, __shfl_xor(pmax, 32));
      const float mnew = fmaxf(mrun, pmax);
      const float resc = __expf(mrun - mnew);
      mrun = mnew;
      float rowsum = 0.0f;
#pragma unroll
      for (int fm = 0; fm < 4; ++fm)
#pragma unroll
        for (int r = 0; r < 4; ++r) {
          const float p = __expf(s[fm][r] - mnew);
          s[fm][r] = p;
          rowsum += p;
        }
      rowsum += __shfl_xor(rowsum, 16);
      rowsum += __shfl_xor(rowsum, 32);
      ell = ell * resc + rowsum;
#pragma unroll
      for (int fm = 0; fm < 8; ++fm) o[fm] *= resc;

      bf16x8 pb[2];
#pragma unroll
      for (int k2 = 0; k2 < 2; ++k2) {
        float va[4], vb[4];
#pragma unroll
        for (int r = 0; r < 4; ++r) {
          const float t0 = __shfl(s[k2 * 2][r], srcA);
          const float t1 = __shfl(s[k2 * 2 + 1][r], srcA);
          va[r] = hi ? t1 : t0;
          const float u0 = __shfl(s[k2 * 2][r], srcB);
          const float u1 = __shfl(s[k2 * 2 + 1][r], srcB);
          vb[r] = hi ? u1 : u0;
        }
        bf16x8 pv;
        pv[0] = (__bf16)va[0]; pv[1] = (__bf16)va[1];
        pv[2] = (__bf16)va[2]; pv[3] = (__bf16)va[3];
        pv[4] = (__bf16)vb[0]; pv[5] = (__bf16)vb[1];
        pv[6] = (__bf16)vb[2]; pv[7] = (__bf16)vb[3];
        pb[k2] = pv;
      }
#pragma unroll
      for (int fm = 0; fm < 8; ++fm) {
        const unsigned short* vr = &Vs[buf][(fm * 16 + c) * 64];
#pragma unroll
        for (int k2 = 0; k2 < 2; ++k2) {
          bf16x8 av = *(const bf16x8*)(vr + ((k2 * 4 + g) ^ cs7) * 8);
          o[fm] = __builtin_amdgcn_mfma_f32_16x16x32_bf16(av, pb[k2], o[fm], 0, 0, 0);
        }
      }
      asm volatile("s_waitcnt vmcnt(0)" ::: "memory");
      __syncthreads();
      buf ^= 1;
    }

    const float inv = 1.0f / ell;
    unsigned short* outp = ctx + (long)(b * T_SEQ + q) * D_MODEL + h * D_HEAD;
#pragma unroll
    for (int fm = 0; fm < 8; ++fm) {
      ushort4 pk;
      pk.x = f2bf(o[fm][0] * inv);
      pk.y = f2bf(o[fm][1] * inv);
      pk.z = f2bf(o[fm][2] * inv);
      pk.w = f2bf(o[fm][3] * inv);
      *(ushort4*)(outp + fm * 16 + 4 * g) = pk;
    }
  }
}

// ---------------------------------------------------------------------------
extern "C" void kernel_launch(void* const* d_in, const int* in_sizes, int n_in,
                              void* d_out, int out_size, void* d_ws, size_t ws_size,
                              hipStream_t stream) {
  const float* x = (const float*)d_in[0];
  const float* w_qkv = (const float*)d_in[1];
  const float* w_out = (const float*)d_in[2];
  const float* g1 = (const float*)d_in[3];
  const float* g2 = (const float*)d_in[4];
  const float* w_g = (const float*)d_in[5];
  const float* w_u = (const float*)d_in[6];
  const float* w_o = (const float*)d_in[7];
  float* out = (float*)d_out;

  char* ws = (char*)d_ws;
  size_t off = 0;
  auto take = [&](size_t bytes) {
    char* p = ws + off;
    off += (bytes + 255) & ~(size_t)255;
    return p;
  };

  // weight region (phase A and phase B alias the same memory)
  char* Wreg = take((size_t)3 * D_FF * D_MODEL * 2);  // 100.66 MB
  unsigned short* wTqkv = (unsigned short*)Wreg;
  unsigned short* wTout = (unsigned short*)(Wreg + (size_t)3 * D_MODEL * D_MODEL * 2);
  unsigned short* wTg = (unsigned short*)Wreg;
  unsigned short* wTu = (unsigned short*)(Wreg + (size_t)D_FF * D_MODEL * 2);
  unsigned short* wTo = (unsigned short*)(Wreg + (size_t)2 * D_FF * D_MODEL * 2);

  // activation region (phase A and phase B alias the same memory)
  const size_t qkv_b = (size_t)BT * 3 * D_MODEL * 2;
  const size_t vt_b = (size_t)B_SZ * N_HEADS * D_HEAD * T_SEQ * 2;
  const size_t ctx_b = (size_t)BT * D_MODEL * 2;
  char* AR = take(qkv_b + vt_b + ctx_b);  // 83.9 MB
  unsigned short* qkvb = (unsigned short*)AR;
  unsigned short* vtb = (unsigned short*)(AR + qkv_b);
  unsigned short* ctxb = (unsigned short*)(AR + qkv_b + vt_b);
  unsigned short* gbuf = (unsigned short*)AR;                                  // 33.6 MB
  unsigned short* ubuf = (unsigned short*)(AR + (size_t)BT * (D_FF / 2) * 2);  // 33.6 MB

  float* x1 = (float*)take((size_t)BT * D_MODEL * 4);
  unsigned short* hb = (unsigned short*)take((size_t)BT * D_MODEL * 2);
  float* cost = (float*)take((size_t)T_SEQ * 64 * 4);
  float* sint = (float*)take((size_t)T_SEQ * 64 * 4);

  const dim3 tb(32, 8);

  // ---- phase A: attention ----
  transpose_cast_kernel<<<dim3(3 * D_MODEL / 32, D_MODEL / 32), tb, 0, stream>>>(w_qkv, wTqkv, D_MODEL, 3 * D_MODEL);
  transpose_cast_kernel<<<dim3(D_MODEL / 32, D_MODEL / 32), tb, 0, stream>>>(w_out, wTout, D_MODEL, D_MODEL);
  rope_tables_kernel<<<T_SEQ * 64 / 256, 256, 0, stream>>>(cost, sint);

  rmsnorm_cast_kernel<<<BT, 256, 0, stream>>>(x, g1, hb);
  // QKV: nbm=16, nbn=24 -> 384 blocks, XCD rect 8x6
  gemm8_kernel<0><<<384, 512, 0, stream>>>(
      hb, wTqkv, qkvb, nullptr, BT, 3 * D_MODEL, D_MODEL, D_MODEL, D_MODEL, 3 * D_MODEL, 8, 6);
  rope_apply_kernel<<<(BT * N_HEADS * 64 * 2) / 256, 256, 0, stream>>>(qkvb, cost, sint);
  vtrans_kernel<<<dim3(T_SEQ / 32, D_HEAD / 32, B_SZ * N_HEADS), tb, 0, stream>>>(qkvb, vtb);
  attn_kernel<<<dim3(NT / 2, N_HEADS, B_SZ), 256, 0, stream>>>(qkvb, vtb, ctxb);
  // out-proj: 128^2 k-slice; nbm=32, nbn=16 -> 512 blocks, chunk 8x8
  gemm_ks_kernel<1, 2, 2, 4, 4><<<512, 256, 0, stream>>>(
      ctxb, wTout, x1, x, BT, D_MODEL, D_MODEL, D_MODEL, D_MODEL, D_MODEL, 8, 8);

  // ---- phase B: MLP, N-halved (M=4096 everywhere) ----
  transpose_cast_kernel<<<dim3(D_FF / 32, D_MODEL / 32), tb, 0, stream>>>(w_g, wTg, D_MODEL, D_FF);
  transpose_cast_kernel<<<dim3(D_FF / 32, D_MODEL / 32), tb, 0, stream>>>(w_u, wTu, D_MODEL, D_FF);
  transpose_cast_kernel<<<dim3(D_MODEL / 32, D_FF / 32), tb, 0, stream>>>(w_o, wTo, D_FF, D_MODEL);
  rmsnorm_cast_kernel<<<BT, 256, 0, stream>>>(x1, g2, hb);

  const int NH = D_FF / 2;  // 4096 ff-columns per half
  for (int half = 0; half < 2; ++half) {
    const unsigned short* wTu_h = wTu + (size_t)half * NH * D_MODEL;
    const unsigned short* wTg_h = wTg + (size_t)half * NH * D_MODEL;
    const unsigned short* wTo_h = wTo + (size_t)half * NH;  // K-slice of [2048][8192]
    // up half: nbm=16, nbn=16 -> 256 blocks, XCD rect 4x8
    gemm8_kernel<0><<<256, 512, 0, stream>>>(
        hb, wTu_h, ubuf, nullptr, BT, NH, D_MODEL, D_MODEL, D_MODEL, NH, 4, 8);
    // gate half + fused SwiGLU (reads ubuf)
    gemm8_kernel<2><<<256, 512, 0, stream>>>(
        hb, wTg_h, gbuf, ubuf, BT, NH, D_MODEL, D_MODEL, D_MODEL, NH, 4, 8);
    // down half: 128^2 k-slice; nbm=32, nbn=16 -> 512 blocks, chunk 8x8
    gemm_ks_kernel<1, 2, 2, 4, 4><<<512, 256, 0, stream>>>(
        gbuf, wTo_h, out, (half == 0) ? x1 : out, BT, D_MODEL, NH, NH, D_FF, D_MODEL, 8, 8);
  }
}

// Round 11
// 803.645 us; speedup vs baseline: 1.2496x; 1.0498x over previous
//
#include <hip/hip_runtime.h>

typedef __bf16 bf16x8 __attribute__((ext_vector_type(8)));
typedef float f32x4 __attribute__((ext_vector_type(4)));
typedef unsigned short u16x8 __attribute__((ext_vector_type(8)));

#define B_SZ 2
#define T_SEQ 2048
#define D_MODEL 2048
#define N_HEADS 16
#define D_HEAD 128
#define D_FF 8192
#define BT (B_SZ * T_SEQ)
#define NT (T_SEQ / 64)

__device__ __forceinline__ unsigned short f2bf(float f) {
  unsigned int u = __builtin_bit_cast(unsigned int, f);
  u += 0x7FFFu + ((u >> 16) & 1u);
  return (unsigned short)(u >> 16);
}
__device__ __forceinline__ float bf2f(unsigned short h) {
  unsigned int u = ((unsigned int)h) << 16;
  return __builtin_bit_cast(float, u);
}

__device__ __forceinline__ void load_lds16(const void* g, void* l) {
  __builtin_amdgcn_global_load_lds(
      (const __attribute__((address_space(1))) unsigned int*)g,
      (__attribute__((address_space(3))) unsigned int*)l, 16, 0, 0);
}

template <int N>
__device__ __forceinline__ void vm_gate() {
  if constexpr (N <= 0)
    asm volatile("s_waitcnt vmcnt(0)" ::: "memory");
  else if constexpr (N == 2)
    asm volatile("s_waitcnt vmcnt(2)" ::: "memory");
  else if constexpr (N == 3)
    asm volatile("s_waitcnt vmcnt(3)" ::: "memory");
  else if constexpr (N == 4)
    asm volatile("s_waitcnt vmcnt(4)" ::: "memory");
  else if constexpr (N == 6)
    asm volatile("s_waitcnt vmcnt(6)" ::: "memory");
  else
    asm volatile("s_waitcnt vmcnt(8)" ::: "memory");
}

// ---------------- transpose + cast: in fp32 [R][C] -> out bf16 [C][R] -------
__global__ __launch_bounds__(256) void transpose_cast_kernel(
    const float* __restrict__ in, unsigned short* __restrict__ out, int R, int C) {
  __shared__ float tile[32][33];
  const int tx = threadIdx.x, ty = threadIdx.y;
  const int c0 = blockIdx.x * 32, r0 = blockIdx.y * 32;
#pragma unroll
  for (int i = 0; i < 4; ++i)
    tile[ty + 8 * i][tx] = in[(long)(r0 + ty + 8 * i) * C + c0 + tx];
  __syncthreads();
#pragma unroll
  for (int i = 0; i < 4; ++i)
    out[(long)(c0 + ty + 8 * i) * R + r0 + tx] = f2bf(tile[tx][ty + 8 * i]);
}

// ---------------- RMSNorm fp32 row -> bf16 ----------------------------------
__global__ __launch_bounds__(256) void rmsnorm_cast_kernel(
    const float* __restrict__ x, const float* __restrict__ gw,
    unsigned short* __restrict__ out) {
  const int row = blockIdx.x;
  const int tid = threadIdx.x;
  const float* xr = x + (long)row * D_MODEL;
  float4 a = *(const float4*)(xr + tid * 8);
  float4 b = *(const float4*)(xr + tid * 8 + 4);
  float ss = a.x * a.x + a.y * a.y + a.z * a.z + a.w * a.w +
             b.x * b.x + b.y * b.y + b.z * b.z + b.w * b.w;
#pragma unroll
  for (int d = 1; d < 64; d <<= 1) ss += __shfl_xor(ss, d);
  __shared__ float part[4];
  if ((tid & 63) == 0) part[tid >> 6] = ss;
  __syncthreads();
  ss = part[0] + part[1] + part[2] + part[3];
  const float rs = rsqrtf(ss * (1.0f / D_MODEL) + 1e-6f);
  float4 g0 = *(const float4*)(gw + tid * 8);
  float4 g1 = *(const float4*)(gw + tid * 8 + 4);
  ushort4 o0, o1;
  o0.x = f2bf(a.x * rs * g0.x); o0.y = f2bf(a.y * rs * g0.y);
  o0.z = f2bf(a.z * rs * g0.z); o0.w = f2bf(a.w * rs * g0.w);
  o1.x = f2bf(b.x * rs * g1.x); o1.y = f2bf(b.y * rs * g1.y);
  o1.z = f2bf(b.z * rs * g1.z); o1.w = f2bf(b.w * rs * g1.w);
  unsigned short* op = out + (long)row * D_MODEL + tid * 8;
  *(ushort4*)op = o0;
  *(ushort4*)(op + 4) = o1;
}

// ---------------- k-slice-ring pipelined GEMM (champion schedule) -----------
// C[M,N] = A[M,K] @ Bt[N,K]^T, bf16 in, fp32 acc.
// Geometry: WMxWN waves, per-wave FMxFN 16x16 frags; BM=WM*FM*16, BN=WN*FN*16.
// 4 k-slice slots (32-k each) per operand; stage slice s+3 during compute of
// slice s; counted vmcnt gate = 2*LPS (LPS = loads/slice) so slice s+1 is
// provably landed at each iteration's barrier; one barrier per slice.
// Rect XCD chunking: bid&7 = XCD owns cm x cn tile rectangle.
// Instances: <2,4,8,4> = 256x256 (LPS=4, gates 8/4/0 — identical to the
// 804-us champion);  <4,2,4,4> = 256x128 (LPS=3, gates 6/3/0) for N=2048
// outputs: balanced 256-block grids with 25% less panel re-staging than 128².
template <int EPI, int WM, int WN, int FM, int FN>
__global__ __launch_bounds__(WM * WN * 64, 2) void gemm_ks_kernel(
    const unsigned short* __restrict__ A, const unsigned short* __restrict__ Bt,
    void* __restrict__ Cout, const void* __restrict__ aux,
    int M, int N, int K, int lda, int ldb, int ldc, int cm, int cn) {
  constexpr int THREADS = WM * WN * 64;
  constexpr int BM = WM * FM * 16;
  constexpr int BN = WN * FN * 16;
  constexpr int ASLOT = BM * 32;
  constexpr int BSLOT = BN * 32;
  constexpr int RPR = THREADS / 4;
  constexpr int LPS = BM / RPR + BN / RPR;  // loads per slice per thread
  __shared__ unsigned short As[4 * ASLOT];
  __shared__ unsigned short Bs[4 * BSLOT];

  const int tid = threadIdx.x;
  const int lane = tid & 63, g = lane >> 4, c = lane & 15;
  const int w = tid >> 6, wr = w / WN, wc = w % WN;

  const int nbn = N / BN;
  const int bid = (int)blockIdx.x;
  const int xcd = bid & 7, idx = bid >> 3;
  const int chn = nbn / cn;
  const int crow = xcd / chn, ccol = xcd % chn;
  const int mr = idx / cn, nc2 = idx % cn;
  const int m0 = (crow * cm + mr) * BM;
  const int n0 = (ccol * cn + nc2) * BN;

  const int nks = K >> 5;
  const int srow = tid >> 2;
  const int kq8 = (tid & 3) * 8;
  const unsigned short* A_ = A + (long)m0 * lda;
  const unsigned short* B_ = Bt + (long)n0 * ldb;

  auto stage = [&](int s) {
    const int slot = s & 3;
    const long kofs = (long)s * 32 + kq8;
#pragma unroll
    for (int j = 0; j < BM / RPR; ++j)
      load_lds16(A_ + (long)(j * RPR + srow) * lda + kofs,
                 &As[slot * ASLOT + (j * THREADS + tid) * 8]);
#pragma unroll
    for (int j = 0; j < BN / RPR; ++j)
      load_lds16(B_ + (long)(j * RPR + srow) * ldb + kofs,
                 &Bs[slot * BSLOT + (j * THREADS + tid) * 8]);
  };

  f32x4 acc[FM][FN] = {};

  stage(0);
  if (nks > 1) stage(1);
  if (nks > 2) stage(2);
  vm_gate<2 * LPS>();
  __builtin_amdgcn_sched_barrier(0);
  __builtin_amdgcn_s_barrier();

  for (int s = 0; s < nks; ++s) {
    const int slot = s & 3;
    const unsigned short* Ap = &As[slot * ASLOT] + (wr * FM * 16 + c) * 32 + g * 8;
    const unsigned short* Bp = &Bs[slot * BSLOT] + (wc * FN * 16 + c) * 32 + g * 8;
    bf16x8 fa[FM], fb[FN];
#pragma unroll
    for (int fm = 0; fm < FM; ++fm) fa[fm] = *(const bf16x8*)(Ap + fm * 512);
#pragma unroll
    for (int fn = 0; fn < FN; ++fn) fb[fn] = *(const bf16x8*)(Bp + fn * 512);
    if (s + 3 < nks) stage(s + 3);
    __builtin_amdgcn_s_setprio(1);
#pragma unroll
    for (int fm = 0; fm < FM; ++fm)
#pragma unroll
      for (int fn = 0; fn < FN; ++fn)
        acc[fm][fn] = __builtin_amdgcn_mfma_f32_16x16x32_bf16(fa[fm], fb[fn], acc[fm][fn], 0, 0, 0);
    __builtin_amdgcn_s_setprio(0);
    if (s + 1 == nks) break;
    if (s <= nks - 4)
      vm_gate<2 * LPS>();
    else if (s == nks - 3)
      vm_gate<LPS>();
    else
      vm_gate<0>();
    __builtin_amdgcn_sched_barrier(0);
    __builtin_amdgcn_s_barrier();
  }

#pragma unroll
  for (int fm = 0; fm < FM; ++fm) {
#pragma unroll
    for (int r = 0; r < 4; ++r) {
      const int row = m0 + wr * FM * 16 + fm * 16 + 4 * g + r;
#pragma unroll
      for (int fn = 0; fn < FN; ++fn) {
        const int col = n0 + wc * FN * 16 + fn * 16 + c;
        const long idx2 = (long)row * ldc + col;
        float v = acc[fm][fn][r];
        if constexpr (EPI == 0) {
          ((unsigned short*)Cout)[idx2] = f2bf(v);
        } else if constexpr (EPI == 1) {
          ((float*)Cout)[idx2] = v + ((const float*)aux)[idx2];
        } else {
          const float u = bf2f(((const unsigned short*)aux)[idx2]);
          const float sg = v / (1.0f + __expf(-v));
          ((unsigned short*)Cout)[idx2] = f2bf(sg * u);
        }
      }
    }
  }
}

// ---------------- RoPE tables -----------------------------------------------
__global__ void rope_tables_kernel(float* __restrict__ cost, float* __restrict__ sint) {
  const int idx = blockIdx.x * 256 + threadIdx.x;  // T*64
  const int t = idx >> 6, i = idx & 63;
  const float invf = powf(10000.0f, -(float)i * (1.0f / 64.0f));
  const float ang = (float)t * invf;
  cost[idx] = cosf(ang);
  sint[idx] = sinf(ang);
}

// ---------------- RoPE apply in-place on q,k halves of qkv(bf16) ------------
__global__ __launch_bounds__(256) void rope_apply_kernel(
    unsigned short* __restrict__ qkv, const float* __restrict__ cost,
    const float* __restrict__ sint) {
  const long idx = (long)blockIdx.x * 256 + threadIdx.x;  // BT*16*64*2
  const int i = idx & 63;
  const int h = (idx >> 6) & 15;
  const int qk = (idx >> 10) & 1;
  const int row = idx >> 11;          // 0..BT-1
  const int t = row & (T_SEQ - 1);
  unsigned short* p = qkv + (long)row * (3 * D_MODEL) + qk * D_MODEL + h * D_HEAD + i;
  const float a = bf2f(p[0]);
  const float b = bf2f(p[64]);
  const float cv = cost[t * 64 + i];
  const float sv = sint[t * 64 + i];
  p[0] = f2bf(a * cv - b * sv);
  p[64] = f2bf(b * cv + a * sv);
}

// ---------------- V transpose: qkv v-part -> vt [B,H,128,T] bf16 ------------
__global__ __launch_bounds__(256) void vtrans_kernel(
    const unsigned short* __restrict__ qkv, unsigned short* __restrict__ vt) {
  __shared__ unsigned short tile[32][33];
  const int tx = threadIdx.x, ty = threadIdx.y;
  const int t0 = blockIdx.x * 32, d0 = blockIdx.y * 32;
  const int bh = blockIdx.z;  // b*16+h
  const int b = bh >> 4, h = bh & 15;
#pragma unroll
  for (int i = 0; i < 4; ++i)
    tile[ty + 8 * i][tx] =
        qkv[(long)(b * T_SEQ + t0 + ty + 8 * i) * (3 * D_MODEL) + 2 * D_MODEL + h * D_HEAD + d0 + tx];
  __syncthreads();
#pragma unroll
  for (int i = 0; i < 4; ++i)
    vt[((long)bh * D_HEAD + d0 + ty + 8 * i) * T_SEQ + t0 + tx] = tile[tx][ty + 8 * i];
}

// ---------------- Flash attention (causal), swapped-QK^T --------------------
__global__ __launch_bounds__(256) void attn_kernel(
    const unsigned short* __restrict__ qkv, const unsigned short* __restrict__ vt,
    unsigned short* __restrict__ ctx) {
  __shared__ unsigned short Ks[2][64 * 128];
  __shared__ unsigned short Vs[2][128 * 64];
  const int h = blockIdx.y, b = blockIdx.z;
  const int tid = threadIdx.x;
  const int w = tid >> 6, lane = tid & 63, g = lane >> 4, c = lane & 15;
  const float scale = 0.08838834764831845f;  // 128^-0.5
  const int srcA = (2 * (g & 1)) * 16 + c;
  const int srcB = srcA + 16;
  const bool hi = (g >> 1) != 0;
  const int bh = b * N_HEADS + h;

  const int ssk = (tid & 15) ^ ((tid >> 4) & 7);
  const int ssv = (tid & 7) ^ ((tid >> 3) & 7);
  const unsigned short* Kg = qkv + (long)b * T_SEQ * 3 * D_MODEL + D_MODEL + (long)h * D_HEAD;
  const unsigned short* Vg = vt + (long)bh * D_HEAD * T_SEQ;

  auto stage = [&](int kv0, int bufi) {
#pragma unroll
    for (int i = 0; i < 4; ++i) {
      const int rowk = i * 16 + (tid >> 4);
      load_lds16(Kg + (long)(kv0 + rowk) * (3 * D_MODEL) + ssk * 8,
                 &Ks[bufi][(i * 256 + tid) * 8]);
    }
#pragma unroll
    for (int i = 0; i < 4; ++i) {
      const int rowv = i * 32 + (tid >> 3);
      load_lds16(Vg + (long)rowv * T_SEQ + kv0 + ssv * 8,
                 &Vs[bufi][(i * 256 + tid) * 8]);
    }
  };

  const int cs7 = c & 7;

  for (int pass = 0; pass < 2; ++pass) {
    const int qt = pass ? (NT - 1 - blockIdx.x) : blockIdx.x;
    const int q = qt * 64 + w * 16 + c;

    bf16x8 fq[4];
    const long rowQ = (long)(b * T_SEQ + q) * (3 * D_MODEL) + h * D_HEAD;
#pragma unroll
    for (int ks = 0; ks < 4; ++ks)
      fq[ks] = *(const bf16x8*)(qkv + rowQ + ks * 32 + g * 8);

    f32x4 o[8] = {};
    float mrun = -INFINITY, ell = 0.0f;

    stage(0, 0);
    asm volatile("s_waitcnt vmcnt(0)" ::: "memory");
    __syncthreads();
    int buf = 0;

    for (int kt = 0; kt <= qt; ++kt) {
      const int kv0 = kt * 64;
      if (kt < qt) stage(kv0 + 64, buf ^ 1);

      f32x4 s[4] = {};
#pragma unroll
      for (int fm = 0; fm < 4; ++fm) {
        const unsigned short* kr = &Ks[buf][(fm * 16 + c) * 128];
#pragma unroll
        for (int ks = 0; ks < 4; ++ks) {
          bf16x8 ak = *(const bf16x8*)(kr + ((ks * 4 + g) ^ cs7) * 8);
          s[fm] = __builtin_amdgcn_mfma_f32_16x16x32_bf16(ak, fq[ks], s[fm], 0, 0, 0);
        }
      }
      float pmax = -INFINITY;
      const bool diag = (kt == qt);
#pragma unroll
      for (int fm = 0; fm < 4; ++fm)
#pragma unroll
        for (int r = 0; r < 4; ++r) {
          float sv = s[fm][r] * scale;
          if (diag) {
            const int kp = kv0 + fm * 16 + 4 * g + r;
            if (kp > q) sv = -INFINITY;
          }
          s[fm][r] = sv;
          pmax = fmaxf(pmax, sv);
        }
      pmax = fmaxf(pmax, __shfl_xor(pmax, 16));
      pmax = fmaxf(pmax, __shfl_xor(pmax, 32));
      const float mnew = fmaxf(mrun, pmax);
      const float resc = __expf(mrun - mnew);
      mrun = mnew;
      float rowsum = 0.0f;
#pragma unroll
      for (int fm = 0; fm < 4; ++fm)
#pragma unroll
        for (int r = 0; r < 4; ++r) {
          const float p = __expf(s[fm][r] - mnew);
          s[fm][r] = p;
          rowsum += p;
        }
      rowsum += __shfl_xor(rowsum, 16);
      rowsum += __shfl_xor(rowsum, 32);
      ell = ell * resc + rowsum;
#pragma unroll
      for (int fm = 0; fm < 8; ++fm) o[fm] *= resc;

      bf16x8 pb[2];
#pragma unroll
      for (int k2 = 0; k2 < 2; ++k2) {
        float va[4], vb[4];
#pragma unroll
        for (int r = 0; r < 4; ++r) {
          const float t0 = __shfl(s[k2 * 2][r], srcA);
          const float t1 = __shfl(s[k2 * 2 + 1][r], srcA);
          va[r] = hi ? t1 : t0;
          const float u0 = __shfl(s[k2 * 2][r], srcB);
          const float u1 = __shfl(s[k2 * 2 + 1][r], srcB);
          vb[r] = hi ? u1 : u0;
        }
        bf16x8 pv;
        pv[0] = (__bf16)va[0]; pv[1] = (__bf16)va[1];
        pv[2] = (__bf16)va[2]; pv[3] = (__bf16)va[3];
        pv[4] = (__bf16)vb[0]; pv[5] = (__bf16)vb[1];
        pv[6] = (__bf16)vb[2]; pv[7] = (__bf16)vb[3];
        pb[k2] = pv;
      }
#pragma unroll
      for (int fm = 0; fm < 8; ++fm) {
        const unsigned short* vr = &Vs[buf][(fm * 16 + c) * 64];
#pragma unroll
        for (int k2 = 0; k2 < 2; ++k2) {
          bf16x8 av = *(const bf16x8*)(vr + ((k2 * 4 + g) ^ cs7) * 8);
          o[fm] = __builtin_amdgcn_mfma_f32_16x16x32_bf16(av, pb[k2], o[fm], 0, 0, 0);
        }
      }
      asm volatile("s_waitcnt vmcnt(0)" ::: "memory");
      __syncthreads();
      buf ^= 1;
    }

    const float inv = 1.0f / ell;
    unsigned short* outp = ctx + (long)(b * T_SEQ + q) * D_MODEL + h * D_HEAD;
#pragma unroll
    for (int fm = 0; fm < 8; ++fm) {
      ushort4 pk;
      pk.x = f2bf(o[fm][0] * inv);
      pk.y = f2bf(o[fm][1] * inv);
      pk.z = f2bf(o[fm][2] * inv);
      pk.w = f2bf(o[fm][3] * inv);
      *(ushort4*)(outp + fm * 16 + 4 * g) = pk;
    }
  }
}

// ---------------------------------------------------------------------------
extern "C" void kernel_launch(void* const* d_in, const int* in_sizes, int n_in,
                              void* d_out, int out_size, void* d_ws, size_t ws_size,
                              hipStream_t stream) {
  const float* x = (const float*)d_in[0];
  const float* w_qkv = (const float*)d_in[1];
  const float* w_out = (const float*)d_in[2];
  const float* g1 = (const float*)d_in[3];
  const float* g2 = (const float*)d_in[4];
  const float* w_g = (const float*)d_in[5];
  const float* w_u = (const float*)d_in[6];
  const float* w_o = (const float*)d_in[7];
  float* out = (float*)d_out;

  char* ws = (char*)d_ws;
  size_t off = 0;
  auto take = [&](size_t bytes) {
    char* p = ws + off;
    off += (bytes + 255) & ~(size_t)255;
    return p;
  };

  // weight region (phase A and phase B alias the same memory)
  char* Wreg = take((size_t)3 * D_FF * D_MODEL * 2);  // 100.66 MB
  unsigned short* wTqkv = (unsigned short*)Wreg;
  unsigned short* wTout = (unsigned short*)(Wreg + (size_t)3 * D_MODEL * D_MODEL * 2);
  unsigned short* wTg = (unsigned short*)Wreg;
  unsigned short* wTu = (unsigned short*)(Wreg + (size_t)D_FF * D_MODEL * 2);
  unsigned short* wTo = (unsigned short*)(Wreg + (size_t)2 * D_FF * D_MODEL * 2);

  // activation region (phase A and phase B alias the same memory)
  const size_t qkv_b = (size_t)BT * 3 * D_MODEL * 2;
  const size_t vt_b = (size_t)B_SZ * N_HEADS * D_HEAD * T_SEQ * 2;
  const size_t ctx_b = (size_t)BT * D_MODEL * 2;
  char* AR = take(qkv_b + vt_b + ctx_b);  // 83.9 MB
  unsigned short* qkvb = (unsigned short*)AR;
  unsigned short* vtb = (unsigned short*)(AR + qkv_b);
  unsigned short* ctxb = (unsigned short*)(AR + qkv_b + vt_b);
  unsigned short* gbuf = (unsigned short*)AR;                                  // 33.6 MB
  unsigned short* ubuf = (unsigned short*)(AR + (size_t)BT * (D_FF / 2) * 2);  // 33.6 MB

  float* x1 = (float*)take((size_t)BT * D_MODEL * 4);
  unsigned short* hb = (unsigned short*)take((size_t)BT * D_MODEL * 2);
  float* cost = (float*)take((size_t)T_SEQ * 64 * 4);
  float* sint = (float*)take((size_t)T_SEQ * 64 * 4);

  const dim3 tb(32, 8);

  // ---- phase A: attention ----
  transpose_cast_kernel<<<dim3(3 * D_MODEL / 32, D_MODEL / 32), tb, 0, stream>>>(w_qkv, wTqkv, D_MODEL, 3 * D_MODEL);
  transpose_cast_kernel<<<dim3(D_MODEL / 32, D_MODEL / 32), tb, 0, stream>>>(w_out, wTout, D_MODEL, D_MODEL);
  rope_tables_kernel<<<T_SEQ * 64 / 256, 256, 0, stream>>>(cost, sint);

  rmsnorm_cast_kernel<<<BT, 256, 0, stream>>>(x, g1, hb);
  // QKV: 256^2 k-slice kernel; nbm=16, nbn=24 -> 384 blocks, XCD rect 8x6
  gemm_ks_kernel<0, 2, 4, 8, 4><<<384, 512, 0, stream>>>(
      hb, wTqkv, qkvb, nullptr, BT, 3 * D_MODEL, D_MODEL, D_MODEL, D_MODEL, 3 * D_MODEL, 8, 6);
  rope_apply_kernel<<<(BT * N_HEADS * 64 * 2) / 256, 256, 0, stream>>>(qkvb, cost, sint);
  vtrans_kernel<<<dim3(T_SEQ / 32, D_HEAD / 32, B_SZ * N_HEADS), tb, 0, stream>>>(qkvb, vtb);
  attn_kernel<<<dim3(NT / 2, N_HEADS, B_SZ), 256, 0, stream>>>(qkvb, vtb, ctxb);
  // out-proj: 256x128 k-slice; nbm=16, nbn=16 -> 256 blocks, rect 8x4
  gemm_ks_kernel<1, 4, 2, 4, 4><<<256, 512, 0, stream>>>(
      ctxb, wTout, x1, x, BT, D_MODEL, D_MODEL, D_MODEL, D_MODEL, D_MODEL, 8, 4);

  // ---- phase B: MLP, N-halved (M=4096 everywhere) ----
  transpose_cast_kernel<<<dim3(D_FF / 32, D_MODEL / 32), tb, 0, stream>>>(w_g, wTg, D_MODEL, D_FF);
  transpose_cast_kernel<<<dim3(D_FF / 32, D_MODEL / 32), tb, 0, stream>>>(w_u, wTu, D_MODEL, D_FF);
  transpose_cast_kernel<<<dim3(D_MODEL / 32, D_FF / 32), tb, 0, stream>>>(w_o, wTo, D_FF, D_MODEL);
  rmsnorm_cast_kernel<<<BT, 256, 0, stream>>>(x1, g2, hb);

  const int NH = D_FF / 2;  // 4096 ff-columns per half
  for (int half = 0; half < 2; ++half) {
    const unsigned short* wTu_h = wTu + (size_t)half * NH * D_MODEL;
    const unsigned short* wTg_h = wTg + (size_t)half * NH * D_MODEL;
    const unsigned short* wTo_h = wTo + (size_t)half * NH;  // K-slice of [2048][8192]
    // up half: 256^2 k-slice; nbm=16, nbn=16 -> 256 blocks, rect 4x8
    gemm_ks_kernel<0, 2, 4, 8, 4><<<256, 512, 0, stream>>>(
        hb, wTu_h, ubuf, nullptr, BT, NH, D_MODEL, D_MODEL, D_MODEL, NH, 4, 8);
    // gate half + fused SwiGLU (reads ubuf)
    gemm_ks_kernel<2, 2, 4, 8, 4><<<256, 512, 0, stream>>>(
        hb, wTg_h, gbuf, ubuf, BT, NH, D_MODEL, D_MODEL, D_MODEL, NH, 4, 8);
    // down half: 256x128 k-slice; nbm=16, nbn=16 -> 256 blocks, rect 8x4 (K=4096)
    gemm_ks_kernel<1, 4, 2, 4, 4><<<256, 512, 0, stream>>>(
        gbuf, wTo_h, out, (half == 0) ? x1 : out, BT, D_MODEL, NH, NH, D_FF, D_MODEL, 8, 4);
  }
}

// Round 12
// 793.477 us; speedup vs baseline: 1.2656x; 1.0128x over previous
//
#include <hip/hip_runtime.h>

typedef __bf16 bf16x8 __attribute__((ext_vector_type(8)));
typedef float f32x4 __attribute__((ext_vector_type(4)));
typedef unsigned short u16x8 __attribute__((ext_vector_type(8)));

#define B_SZ 2
#define T_SEQ 2048
#define D_MODEL 2048
#define N_HEADS 16
#define D_HEAD 128
#define D_FF 8192
#define BT (B_SZ * T_SEQ)
#define NT (T_SEQ / 64)

__device__ __forceinline__ unsigned short f2bf(float f) {
  unsigned int u = __builtin_bit_cast(unsigned int, f);
  u += 0x7FFFu + ((u >> 16) & 1u);
  return (unsigned short)(u >> 16);
}
__device__ __forceinline__ float bf2f(unsigned short h) {
  unsigned int u = ((unsigned int)h) << 16;
  return __builtin_bit_cast(float, u);
}

__device__ __forceinline__ void load_lds16(const void* g, void* l) {
  __builtin_amdgcn_global_load_lds(
      (const __attribute__((address_space(1))) unsigned int*)g,
      (__attribute__((address_space(3))) unsigned int*)l, 16, 0, 0);
}

template <int N>
__device__ __forceinline__ void vm_gate() {
  if constexpr (N <= 0)
    asm volatile("s_waitcnt vmcnt(0)" ::: "memory");
  else if constexpr (N == 2)
    asm volatile("s_waitcnt vmcnt(2)" ::: "memory");
  else if constexpr (N == 3)
    asm volatile("s_waitcnt vmcnt(3)" ::: "memory");
  else if constexpr (N == 4)
    asm volatile("s_waitcnt vmcnt(4)" ::: "memory");
  else if constexpr (N == 6)
    asm volatile("s_waitcnt vmcnt(6)" ::: "memory");
  else
    asm volatile("s_waitcnt vmcnt(8)" ::: "memory");
}

// ---------------- transpose + cast: in fp32 [R][C] -> out bf16 [C][R] -------
__global__ __launch_bounds__(256) void transpose_cast_kernel(
    const float* __restrict__ in, unsigned short* __restrict__ out, int R, int C) {
  __shared__ float tile[32][33];
  const int tx = threadIdx.x, ty = threadIdx.y;
  const int c0 = blockIdx.x * 32, r0 = blockIdx.y * 32;
#pragma unroll
  for (int i = 0; i < 4; ++i)
    tile[ty + 8 * i][tx] = in[(long)(r0 + ty + 8 * i) * C + c0 + tx];
  __syncthreads();
#pragma unroll
  for (int i = 0; i < 4; ++i)
    out[(long)(c0 + ty + 8 * i) * R + r0 + tx] = f2bf(tile[tx][ty + 8 * i]);
}

// ---------------- RMSNorm fp32 row -> bf16 ----------------------------------
__global__ __launch_bounds__(256) void rmsnorm_cast_kernel(
    const float* __restrict__ x, const float* __restrict__ gw,
    unsigned short* __restrict__ out) {
  const int row = blockIdx.x;
  const int tid = threadIdx.x;
  const float* xr = x + (long)row * D_MODEL;
  float4 a = *(const float4*)(xr + tid * 8);
  float4 b = *(const float4*)(xr + tid * 8 + 4);
  float ss = a.x * a.x + a.y * a.y + a.z * a.z + a.w * a.w +
             b.x * b.x + b.y * b.y + b.z * b.z + b.w * b.w;
#pragma unroll
  for (int d = 1; d < 64; d <<= 1) ss += __shfl_xor(ss, d);
  __shared__ float part[4];
  if ((tid & 63) == 0) part[tid >> 6] = ss;
  __syncthreads();
  ss = part[0] + part[1] + part[2] + part[3];
  const float rs = rsqrtf(ss * (1.0f / D_MODEL) + 1e-6f);
  float4 g0 = *(const float4*)(gw + tid * 8);
  float4 g1 = *(const float4*)(gw + tid * 8 + 4);
  ushort4 o0, o1;
  o0.x = f2bf(a.x * rs * g0.x); o0.y = f2bf(a.y * rs * g0.y);
  o0.z = f2bf(a.z * rs * g0.z); o0.w = f2bf(a.w * rs * g0.w);
  o1.x = f2bf(b.x * rs * g1.x); o1.y = f2bf(b.y * rs * g1.y);
  o1.z = f2bf(b.z * rs * g1.z); o1.w = f2bf(b.w * rs * g1.w);
  unsigned short* op = out + (long)row * D_MODEL + tid * 8;
  *(ushort4*)op = o0;
  *(ushort4*)(op + 4) = o1;
}

// ---------------- k-slice-ring pipelined GEMM (champion schedule) -----------
// C[M,N] = A[M,K] @ Bt[N,K]^T, bf16 in, fp32 acc.
// 4 k-slice slots (32-k); stage slice s+3 during compute of slice s; counted
// vmcnt gate 2*LPS (slice s+1 provably landed); one barrier per slice.
// Rect XCD chunking: bid&7 = XCD owns cm x cn tile rectangle.
// DUALA: A comes from A (k < K/2) / A2 (k >= K/2), both with leading dim lda —
// used to run the down-projection as a single K=8192 dispatch over the two
// SwiGLU halves. B always indexes global k (ldb spans full K).
// EPI: 0 bf16 store; 1 fp32 store + fp32 resid; 2 silu(acc)*aux -> bf16
// (Cout == aux is safe: each element read-then-written by exactly one thread).
template <int EPI, int WM, int WN, int FM, int FN, bool DUALA = false>
__global__ __launch_bounds__(WM * WN * 64, 2) void gemm_ks_kernel(
    const unsigned short* __restrict__ A, const unsigned short* __restrict__ Bt,
    void* __restrict__ Cout, const void* __restrict__ aux,
    const unsigned short* __restrict__ A2,
    int M, int N, int K, int lda, int ldb, int ldc, int cm, int cn) {
  constexpr int THREADS = WM * WN * 64;
  constexpr int BM = WM * FM * 16;
  constexpr int BN = WN * FN * 16;
  constexpr int ASLOT = BM * 32;
  constexpr int BSLOT = BN * 32;
  constexpr int RPR = THREADS / 4;
  constexpr int LPS = BM / RPR + BN / RPR;  // loads per slice per thread
  __shared__ unsigned short As[4 * ASLOT];
  __shared__ unsigned short Bs[4 * BSLOT];

  const int tid = threadIdx.x;
  const int lane = tid & 63, g = lane >> 4, c = lane & 15;
  const int w = tid >> 6, wr = w / WN, wc = w % WN;

  const int nbn = N / BN;
  const int bid = (int)blockIdx.x;
  const int xcd = bid & 7, idx = bid >> 3;
  const int chn = nbn / cn;
  const int crow = xcd / chn, ccol = xcd % chn;
  const int mr = idx / cn, nc2 = idx % cn;
  const int m0 = (crow * cm + mr) * BM;
  const int n0 = (ccol * cn + nc2) * BN;

  const int nks = K >> 5;
  const int srow = tid >> 2;
  const int kq8 = (tid & 3) * 8;
  const unsigned short* A_ = A + (long)m0 * lda;
  const unsigned short* A2_ = DUALA ? (A2 + (long)m0 * lda) : nullptr;
  const unsigned short* B_ = Bt + (long)n0 * ldb;

  auto stage = [&](int s) {
    const int slot = s & 3;
    const long k32 = (long)s * 32;
    const unsigned short* Ab;
    long akofs;
    if constexpr (DUALA) {
      const int khalf = K >> 1;
      const bool lo = k32 < khalf;
      Ab = lo ? A_ : A2_;
      akofs = (lo ? k32 : k32 - khalf) + kq8;
    } else {
      Ab = A_;
      akofs = k32 + kq8;
    }
    const long bkofs = k32 + kq8;
#pragma unroll
    for (int j = 0; j < BM / RPR; ++j)
      load_lds16(Ab + (long)(j * RPR + srow) * lda + akofs,
                 &As[slot * ASLOT + (j * THREADS + tid) * 8]);
#pragma unroll
    for (int j = 0; j < BN / RPR; ++j)
      load_lds16(B_ + (long)(j * RPR + srow) * ldb + bkofs,
                 &Bs[slot * BSLOT + (j * THREADS + tid) * 8]);
  };

  f32x4 acc[FM][FN] = {};

  stage(0);
  if (nks > 1) stage(1);
  if (nks > 2) stage(2);
  vm_gate<2 * LPS>();
  __builtin_amdgcn_sched_barrier(0);
  __builtin_amdgcn_s_barrier();

  for (int s = 0; s < nks; ++s) {
    const int slot = s & 3;
    const unsigned short* Ap = &As[slot * ASLOT] + (wr * FM * 16 + c) * 32 + g * 8;
    const unsigned short* Bp = &Bs[slot * BSLOT] + (wc * FN * 16 + c) * 32 + g * 8;
    bf16x8 fa[FM], fb[FN];
#pragma unroll
    for (int fm = 0; fm < FM; ++fm) fa[fm] = *(const bf16x8*)(Ap + fm * 512);
#pragma unroll
    for (int fn = 0; fn < FN; ++fn) fb[fn] = *(const bf16x8*)(Bp + fn * 512);
    if (s + 3 < nks) stage(s + 3);
    __builtin_amdgcn_s_setprio(1);
#pragma unroll
    for (int fm = 0; fm < FM; ++fm)
#pragma unroll
      for (int fn = 0; fn < FN; ++fn)
        acc[fm][fn] = __builtin_amdgcn_mfma_f32_16x16x32_bf16(fa[fm], fb[fn], acc[fm][fn], 0, 0, 0);
    __builtin_amdgcn_s_setprio(0);
    if (s + 1 == nks) break;
    if (s <= nks - 4)
      vm_gate<2 * LPS>();
    else if (s == nks - 3)
      vm_gate<LPS>();
    else
      vm_gate<0>();
    __builtin_amdgcn_sched_barrier(0);
    __builtin_amdgcn_s_barrier();
  }

#pragma unroll
  for (int fm = 0; fm < FM; ++fm) {
#pragma unroll
    for (int r = 0; r < 4; ++r) {
      const int row = m0 + wr * FM * 16 + fm * 16 + 4 * g + r;
#pragma unroll
      for (int fn = 0; fn < FN; ++fn) {
        const int col = n0 + wc * FN * 16 + fn * 16 + c;
        const long idx2 = (long)row * ldc + col;
        float v = acc[fm][fn][r];
        if constexpr (EPI == 0) {
          ((unsigned short*)Cout)[idx2] = f2bf(v);
        } else if constexpr (EPI == 1) {
          ((float*)Cout)[idx2] = v + ((const float*)aux)[idx2];
        } else {
          const float u = bf2f(((const unsigned short*)aux)[idx2]);
          const float sg = v / (1.0f + __expf(-v));
          ((unsigned short*)Cout)[idx2] = f2bf(sg * u);
        }
      }
    }
  }
}

// ---------------- RoPE tables -----------------------------------------------
__global__ void rope_tables_kernel(float* __restrict__ cost, float* __restrict__ sint) {
  const int idx = blockIdx.x * 256 + threadIdx.x;  // T*64
  const int t = idx >> 6, i = idx & 63;
  const float invf = powf(10000.0f, -(float)i * (1.0f / 64.0f));
  const float ang = (float)t * invf;
  cost[idx] = cosf(ang);
  sint[idx] = sinf(ang);
}

// ---------------- RoPE apply in-place on q,k halves of qkv(bf16) ------------
__global__ __launch_bounds__(256) void rope_apply_kernel(
    unsigned short* __restrict__ qkv, const float* __restrict__ cost,
    const float* __restrict__ sint) {
  const long idx = (long)blockIdx.x * 256 + threadIdx.x;  // BT*16*64*2
  const int i = idx & 63;
  const int h = (idx >> 6) & 15;
  const int qk = (idx >> 10) & 1;
  const int row = idx >> 11;          // 0..BT-1
  const int t = row & (T_SEQ - 1);
  unsigned short* p = qkv + (long)row * (3 * D_MODEL) + qk * D_MODEL + h * D_HEAD + i;
  const float a = bf2f(p[0]);
  const float b = bf2f(p[64]);
  const float cv = cost[t * 64 + i];
  const float sv = sint[t * 64 + i];
  p[0] = f2bf(a * cv - b * sv);
  p[64] = f2bf(b * cv + a * sv);
}

// ---------------- V transpose: qkv v-part -> vt [B,H,128,T] bf16 ------------
__global__ __launch_bounds__(256) void vtrans_kernel(
    const unsigned short* __restrict__ qkv, unsigned short* __restrict__ vt) {
  __shared__ unsigned short tile[32][33];
  const int tx = threadIdx.x, ty = threadIdx.y;
  const int t0 = blockIdx.x * 32, d0 = blockIdx.y * 32;
  const int bh = blockIdx.z;  // b*16+h
  const int b = bh >> 4, h = bh & 15;
#pragma unroll
  for (int i = 0; i < 4; ++i)
    tile[ty + 8 * i][tx] =
        qkv[(long)(b * T_SEQ + t0 + ty + 8 * i) * (3 * D_MODEL) + 2 * D_MODEL + h * D_HEAD + d0 + tx];
  __syncthreads();
#pragma unroll
  for (int i = 0; i < 4; ++i)
    vt[((long)bh * D_HEAD + d0 + ty + 8 * i) * T_SEQ + t0 + tx] = tile[tx][ty + 8 * i];
}

// ---------------- Flash attention (causal), swapped-QK^T --------------------
__global__ __launch_bounds__(256) void attn_kernel(
    const unsigned short* __restrict__ qkv, const unsigned short* __restrict__ vt,
    unsigned short* __restrict__ ctx) {
  __shared__ unsigned short Ks[2][64 * 128];
  __shared__ unsigned short Vs[2][128 * 64];
  const int h = blockIdx.y, b = blockIdx.z;
  const int tid = threadIdx.x;
  const int w = tid >> 6, lane = tid & 63, g = lane >> 4, c = lane & 15;
  const float scale = 0.08838834764831845f;  // 128^-0.5
  const int srcA = (2 * (g & 1)) * 16 + c;
  const int srcB = srcA + 16;
  const bool hi = (g >> 1) != 0;
  const int bh = b * N_HEADS + h;

  const int ssk = (tid & 15) ^ ((tid >> 4) & 7);
  const int ssv = (tid & 7) ^ ((tid >> 3) & 7);
  const unsigned short* Kg = qkv + (long)b * T_SEQ * 3 * D_MODEL + D_MODEL + (long)h * D_HEAD;
  const unsigned short* Vg = vt + (long)bh * D_HEAD * T_SEQ;

  auto stage = [&](int kv0, int bufi) {
#pragma unroll
    for (int i = 0; i < 4; ++i) {
      const int rowk = i * 16 + (tid >> 4);
      load_lds16(Kg + (long)(kv0 + rowk) * (3 * D_MODEL) + ssk * 8,
                 &Ks[bufi][(i * 256 + tid) * 8]);
    }
#pragma unroll
    for (int i = 0; i < 4; ++i) {
      const int rowv = i * 32 + (tid >> 3);
      load_lds16(Vg + (long)rowv * T_SEQ + kv0 + ssv * 8,
                 &Vs[bufi][(i * 256 + tid) * 8]);
    }
  };

  const int cs7 = c & 7;

  for (int pass = 0; pass < 2; ++pass) {
    const int qt = pass ? (NT - 1 - blockIdx.x) : blockIdx.x;
    const int q = qt * 64 + w * 16 + c;

    bf16x8 fq[4];
    const long rowQ = (long)(b * T_SEQ + q) * (3 * D_MODEL) + h * D_HEAD;
#pragma unroll
    for (int ks = 0; ks < 4; ++ks)
      fq[ks] = *(const bf16x8*)(qkv + rowQ + ks * 32 + g * 8);

    f32x4 o[8] = {};
    float mrun = -INFINITY, ell = 0.0f;

    stage(0, 0);
    asm volatile("s_waitcnt vmcnt(0)" ::: "memory");
    __syncthreads();
    int buf = 0;

    for (int kt = 0; kt <= qt; ++kt) {
      const int kv0 = kt * 64;
      if (kt < qt) stage(kv0 + 64, buf ^ 1);

      f32x4 s[4] = {};
      __builtin_amdgcn_s_setprio(1);
#pragma unroll
      for (int fm = 0; fm < 4; ++fm) {
        const unsigned short* kr = &Ks[buf][(fm * 16 + c) * 128];
#pragma unroll
        for (int ks = 0; ks < 4; ++ks) {
          bf16x8 ak = *(const bf16x8*)(kr + ((ks * 4 + g) ^ cs7) * 8);
          s[fm] = __builtin_amdgcn_mfma_f32_16x16x32_bf16(ak, fq[ks], s[fm], 0, 0, 0);
        }
      }
      __builtin_amdgcn_s_setprio(0);
      float pmax = -INFINITY;
      const bool diag = (kt == qt);
#pragma unroll
      for (int fm = 0; fm < 4; ++fm)
#pragma unroll
        for (int r = 0; r < 4; ++r) {
          float sv = s[fm][r] * scale;
          if (diag) {
            const int kp = kv0 + fm * 16 + 4 * g + r;
            if (kp > q) sv = -INFINITY;
          }
          s[fm][r] = sv;
          pmax = fmaxf(pmax, sv);
        }
      pmax = fmaxf(pmax, __shfl_xor(pmax, 16));
      pmax = fmaxf(pmax, __shfl_xor(pmax, 32));
      const float mnew = fmaxf(mrun, pmax);
      const float resc = __expf(mrun - mnew);
      mrun = mnew;
      float rowsum = 0.0f;
#pragma unroll
      for (int fm = 0; fm < 4; ++fm)
#pragma unroll
        for (int r = 0; r < 4; ++r) {
          const float p = __expf(s[fm][r] - mnew);
          s[fm][r] = p;
          rowsum += p;
        }
      rowsum += __shfl_xor(rowsum, 16);
      rowsum += __shfl_xor(rowsum, 32);
      ell = ell * resc + rowsum;
#pragma unroll
      for (int fm = 0; fm < 8; ++fm) o[fm] *= resc;

      bf16x8 pb[2];
#pragma unroll
      for (int k2 = 0; k2 < 2; ++k2) {
        float va[4], vb[4];
#pragma unroll
        for (int r = 0; r < 4; ++r) {
          const float t0 = __shfl(s[k2 * 2][r], srcA);
          const float t1 = __shfl(s[k2 * 2 + 1][r], srcA);
          va[r] = hi ? t1 : t0;
          const float u0 = __shfl(s[k2 * 2][r], srcB);
          const float u1 = __shfl(s[k2 * 2 + 1][r], srcB);
          vb[r] = hi ? u1 : u0;
        }
        bf16x8 pv;
        pv[0] = (__bf16)va[0]; pv[1] = (__bf16)va[1];
        pv[2] = (__bf16)va[2]; pv[3] = (__bf16)va[3];
        pv[4] = (__bf16)vb[0]; pv[5] = (__bf16)vb[1];
        pv[6] = (__bf16)vb[2]; pv[7] = (__bf16)vb[3];
        pb[k2] = pv;
      }
      __builtin_amdgcn_s_setprio(1);
#pragma unroll
      for (int fm = 0; fm < 8; ++fm) {
        const unsigned short* vr = &Vs[buf][(fm * 16 + c) * 64];
#pragma unroll
        for (int k2 = 0; k2 < 2; ++k2) {
          bf16x8 av = *(const bf16x8*)(vr + ((k2 * 4 + g) ^ cs7) * 8);
          o[fm] = __builtin_amdgcn_mfma_f32_16x16x32_bf16(av, pb[k2], o[fm], 0, 0, 0);
        }
      }
      __builtin_amdgcn_s_setprio(0);
      asm volatile("s_waitcnt vmcnt(0)" ::: "memory");
      __syncthreads();
      buf ^= 1;
    }

    const float inv = 1.0f / ell;
    unsigned short* outp = ctx + (long)(b * T_SEQ + q) * D_MODEL + h * D_HEAD;
#pragma unroll
    for (int fm = 0; fm < 8; ++fm) {
      ushort4 pk;
      pk.x = f2bf(o[fm][0] * inv);
      pk.y = f2bf(o[fm][1] * inv);
      pk.z = f2bf(o[fm][2] * inv);
      pk.w = f2bf(o[fm][3] * inv);
      *(ushort4*)(outp + fm * 16 + 4 * g) = pk;
    }
  }
}

// ---------------------------------------------------------------------------
// Workspace (~236 MB, aliased):
//   Wreg 100.7 : A = wTqkv(25.2)+wTout(8.4); B = wTg+wTu+wTo (33.6 each)
//   AR    83.9 : A = qkvb(50.3)+vtb(16.8)+ctxb(16.8); B = gbuf0(33.6)+gbuf1(33.6)
//   x1    33.6 (fp32), hb 16.8, tables 1.0
extern "C" void kernel_launch(void* const* d_in, const int* in_sizes, int n_in,
                              void* d_out, int out_size, void* d_ws, size_t ws_size,
                              hipStream_t stream) {
  const float* x = (const float*)d_in[0];
  const float* w_qkv = (const float*)d_in[1];
  const float* w_out = (const float*)d_in[2];
  const float* g1 = (const float*)d_in[3];
  const float* g2 = (const float*)d_in[4];
  const float* w_g = (const float*)d_in[5];
  const float* w_u = (const float*)d_in[6];
  const float* w_o = (const float*)d_in[7];
  float* out = (float*)d_out;

  char* ws = (char*)d_ws;
  size_t off = 0;
  auto take = [&](size_t bytes) {
    char* p = ws + off;
    off += (bytes + 255) & ~(size_t)255;
    return p;
  };

  char* Wreg = take((size_t)3 * D_FF * D_MODEL * 2);  // 100.66 MB
  unsigned short* wTqkv = (unsigned short*)Wreg;
  unsigned short* wTout = (unsigned short*)(Wreg + (size_t)3 * D_MODEL * D_MODEL * 2);
  unsigned short* wTg = (unsigned short*)Wreg;
  unsigned short* wTu = (unsigned short*)(Wreg + (size_t)D_FF * D_MODEL * 2);
  unsigned short* wTo = (unsigned short*)(Wreg + (size_t)2 * D_FF * D_MODEL * 2);

  const size_t qkv_b = (size_t)BT * 3 * D_MODEL * 2;
  const size_t vt_b = (size_t)B_SZ * N_HEADS * D_HEAD * T_SEQ * 2;
  const size_t ctx_b = (size_t)BT * D_MODEL * 2;
  char* AR = take(qkv_b + vt_b + ctx_b);  // 83.9 MB
  unsigned short* qkvb = (unsigned short*)AR;
  unsigned short* vtb = (unsigned short*)(AR + qkv_b);
  unsigned short* ctxb = (unsigned short*)(AR + qkv_b + vt_b);
  unsigned short* gbuf0 = (unsigned short*)AR;                                   // 33.6 MB
  unsigned short* gbuf1 = (unsigned short*)(AR + (size_t)BT * (D_FF / 2) * 2);   // 33.6 MB

  float* x1 = (float*)take((size_t)BT * D_MODEL * 4);
  unsigned short* hb = (unsigned short*)take((size_t)BT * D_MODEL * 2);
  float* cost = (float*)take((size_t)T_SEQ * 64 * 4);
  float* sint = (float*)take((size_t)T_SEQ * 64 * 4);

  const dim3 tb(32, 8);

  // ---- phase A: attention ----
  transpose_cast_kernel<<<dim3(3 * D_MODEL / 32, D_MODEL / 32), tb, 0, stream>>>(w_qkv, wTqkv, D_MODEL, 3 * D_MODEL);
  transpose_cast_kernel<<<dim3(D_MODEL / 32, D_MODEL / 32), tb, 0, stream>>>(w_out, wTout, D_MODEL, D_MODEL);
  rope_tables_kernel<<<T_SEQ * 64 / 256, 256, 0, stream>>>(cost, sint);

  rmsnorm_cast_kernel<<<BT, 256, 0, stream>>>(x, g1, hb);
  // QKV: 256^2; nbm=16, nbn=24 -> 384 blocks, XCD rect 8x6
  gemm_ks_kernel<0, 2, 4, 8, 4><<<384, 512, 0, stream>>>(
      hb, wTqkv, qkvb, nullptr, nullptr, BT, 3 * D_MODEL, D_MODEL, D_MODEL, D_MODEL, 3 * D_MODEL, 8, 6);
  rope_apply_kernel<<<(BT * N_HEADS * 64 * 2) / 256, 256, 0, stream>>>(qkvb, cost, sint);
  vtrans_kernel<<<dim3(T_SEQ / 32, D_HEAD / 32, B_SZ * N_HEADS), tb, 0, stream>>>(qkvb, vtb);
  attn_kernel<<<dim3(NT / 2, N_HEADS, B_SZ), 256, 0, stream>>>(qkvb, vtb, ctxb);
  // out-proj: 256x128; 256 blocks, rect 8x4
  gemm_ks_kernel<1, 4, 2, 4, 4><<<256, 512, 0, stream>>>(
      ctxb, wTout, x1, x, nullptr, BT, D_MODEL, D_MODEL, D_MODEL, D_MODEL, D_MODEL, 8, 4);

  // ---- phase B: MLP ----
  transpose_cast_kernel<<<dim3(D_FF / 32, D_MODEL / 32), tb, 0, stream>>>(w_g, wTg, D_MODEL, D_FF);
  transpose_cast_kernel<<<dim3(D_FF / 32, D_MODEL / 32), tb, 0, stream>>>(w_u, wTu, D_MODEL, D_FF);
  transpose_cast_kernel<<<dim3(D_MODEL / 32, D_FF / 32), tb, 0, stream>>>(w_o, wTo, D_FF, D_MODEL);
  rmsnorm_cast_kernel<<<BT, 256, 0, stream>>>(x1, g2, hb);

  const int NH = D_FF / 2;  // 4096 ff-columns per half
  for (int half = 0; half < 2; ++half) {
    const unsigned short* wTu_h = wTu + (size_t)half * NH * D_MODEL;
    const unsigned short* wTg_h = wTg + (size_t)half * NH * D_MODEL;
    unsigned short* gb = half ? gbuf1 : gbuf0;
    // up half -> gb (raw u)
    gemm_ks_kernel<0, 2, 4, 8, 4><<<256, 512, 0, stream>>>(
        hb, wTu_h, gb, nullptr, nullptr, BT, NH, D_MODEL, D_MODEL, D_MODEL, NH, 4, 8);
    // gate half, in-place SwiGLU: gb <- silu(h@wTg) * gb
    gemm_ks_kernel<2, 2, 4, 8, 4><<<256, 512, 0, stream>>>(
        hb, wTg_h, gb, gb, nullptr, BT, NH, D_MODEL, D_MODEL, D_MODEL, NH, 4, 8);
  }
  // down: single K=8192 dispatch, A = gbuf0 (k<4096) / gbuf1 (k>=4096),
  // B = full wTo [2048][8192]; 256x128 tile, 256 blocks, rect 8x4
  gemm_ks_kernel<1, 4, 2, 4, 4, true><<<256, 512, 0, stream>>>(
      gbuf0, wTo, out, x1, gbuf1, BT, D_MODEL, D_FF, NH, D_FF, D_MODEL, 8, 4);
}

// Round 13
// 778.830 us; speedup vs baseline: 1.2894x; 1.0188x over previous
//
#include <hip/hip_runtime.h>

typedef __bf16 bf16x8 __attribute__((ext_vector_type(8)));
typedef float f32x4 __attribute__((ext_vector_type(4)));
typedef unsigned short u16x8 __attribute__((ext_vector_type(8)));

#define B_SZ 2
#define T_SEQ 2048
#define D_MODEL 2048
#define N_HEADS 16
#define D_HEAD 128
#define D_FF 8192
#define BT (B_SZ * T_SEQ)
#define NT (T_SEQ / 64)

__device__ __forceinline__ unsigned short f2bf(float f) {
  unsigned int u = __builtin_bit_cast(unsigned int, f);
  u += 0x7FFFu + ((u >> 16) & 1u);
  return (unsigned short)(u >> 16);
}
__device__ __forceinline__ float bf2f(unsigned short h) {
  unsigned int u = ((unsigned int)h) << 16;
  return __builtin_bit_cast(float, u);
}

__device__ __forceinline__ void load_lds16(const void* g, void* l) {
  __builtin_amdgcn_global_load_lds(
      (const __attribute__((address_space(1))) unsigned int*)g,
      (__attribute__((address_space(3))) unsigned int*)l, 16, 0, 0);
}

template <int N>
__device__ __forceinline__ void vm_gate() {
  if constexpr (N <= 0)
    asm volatile("s_waitcnt vmcnt(0)" ::: "memory");
  else if constexpr (N == 2)
    asm volatile("s_waitcnt vmcnt(2)" ::: "memory");
  else if constexpr (N == 3)
    asm volatile("s_waitcnt vmcnt(3)" ::: "memory");
  else if constexpr (N == 4)
    asm volatile("s_waitcnt vmcnt(4)" ::: "memory");
  else if constexpr (N == 6)
    asm volatile("s_waitcnt vmcnt(6)" ::: "memory");
  else
    asm volatile("s_waitcnt vmcnt(8)" ::: "memory");
}

// ---------------- transpose + cast: in fp32 [R][C] -> out bf16 [C][R] -------
// 64x64 tile, block (16,16): float4 loads, ushort4 stores (G13-vectorized).
__global__ __launch_bounds__(256) void transpose_cast_kernel(
    const float* __restrict__ in, unsigned short* __restrict__ out, int R, int C) {
  __shared__ float tile[64][65];
  const int tx = threadIdx.x, ty = threadIdx.y;  // [0,16)
  const int c0 = blockIdx.x * 64, r0 = blockIdx.y * 64;
#pragma unroll
  for (int i = 0; i < 4; ++i) {
    const float4 v = *(const float4*)(in + (long)(r0 + ty + 16 * i) * C + c0 + tx * 4);
    float* tr = &tile[ty + 16 * i][tx * 4];
    tr[0] = v.x; tr[1] = v.y; tr[2] = v.z; tr[3] = v.w;
  }
  __syncthreads();
#pragma unroll
  for (int i = 0; i < 4; ++i) {
    const int cc = ty + 16 * i;
    ushort4 o;
    o.x = f2bf(tile[tx * 4 + 0][cc]);
    o.y = f2bf(tile[tx * 4 + 1][cc]);
    o.z = f2bf(tile[tx * 4 + 2][cc]);
    o.w = f2bf(tile[tx * 4 + 3][cc]);
    *(ushort4*)(out + (long)(c0 + cc) * R + r0 + tx * 4) = o;
  }
}

// ---------------- RMSNorm fp32 row -> bf16 ----------------------------------
__global__ __launch_bounds__(256) void rmsnorm_cast_kernel(
    const float* __restrict__ x, const float* __restrict__ gw,
    unsigned short* __restrict__ out) {
  const int row = blockIdx.x;
  const int tid = threadIdx.x;
  const float* xr = x + (long)row * D_MODEL;
  float4 a = *(const float4*)(xr + tid * 8);
  float4 b = *(const float4*)(xr + tid * 8 + 4);
  float ss = a.x * a.x + a.y * a.y + a.z * a.z + a.w * a.w +
             b.x * b.x + b.y * b.y + b.z * b.z + b.w * b.w;
#pragma unroll
  for (int d = 1; d < 64; d <<= 1) ss += __shfl_xor(ss, d);
  __shared__ float part[4];
  if ((tid & 63) == 0) part[tid >> 6] = ss;
  __syncthreads();
  ss = part[0] + part[1] + part[2] + part[3];
  const float rs = rsqrtf(ss * (1.0f / D_MODEL) + 1e-6f);
  float4 g0 = *(const float4*)(gw + tid * 8);
  float4 g1 = *(const float4*)(gw + tid * 8 + 4);
  ushort4 o0, o1;
  o0.x = f2bf(a.x * rs * g0.x); o0.y = f2bf(a.y * rs * g0.y);
  o0.z = f2bf(a.z * rs * g0.z); o0.w = f2bf(a.w * rs * g0.w);
  o1.x = f2bf(b.x * rs * g1.x); o1.y = f2bf(b.y * rs * g1.y);
  o1.z = f2bf(b.z * rs * g1.z); o1.w = f2bf(b.w * rs * g1.w);
  unsigned short* op = out + (long)row * D_MODEL + tid * 8;
  *(ushort4*)op = o0;
  *(ushort4*)(op + 4) = o1;
}

// ---------------- k-slice-ring pipelined GEMM (champion schedule) -----------
template <int EPI, int WM, int WN, int FM, int FN, bool DUALA = false>
__global__ __launch_bounds__(WM * WN * 64, 2) void gemm_ks_kernel(
    const unsigned short* __restrict__ A, const unsigned short* __restrict__ Bt,
    void* __restrict__ Cout, const void* __restrict__ aux,
    const unsigned short* __restrict__ A2,
    int M, int N, int K, int lda, int ldb, int ldc, int cm, int cn) {
  constexpr int THREADS = WM * WN * 64;
  constexpr int BM = WM * FM * 16;
  constexpr int BN = WN * FN * 16;
  constexpr int ASLOT = BM * 32;
  constexpr int BSLOT = BN * 32;
  constexpr int RPR = THREADS / 4;
  constexpr int LPS = BM / RPR + BN / RPR;  // loads per slice per thread
  __shared__ unsigned short As[4 * ASLOT];
  __shared__ unsigned short Bs[4 * BSLOT];

  const int tid = threadIdx.x;
  const int lane = tid & 63, g = lane >> 4, c = lane & 15;
  const int w = tid >> 6, wr = w / WN, wc = w % WN;

  const int nbn = N / BN;
  const int bid = (int)blockIdx.x;
  const int xcd = bid & 7, idx = bid >> 3;
  const int chn = nbn / cn;
  const int crow = xcd / chn, ccol = xcd % chn;
  const int mr = idx / cn, nc2 = idx % cn;
  const int m0 = (crow * cm + mr) * BM;
  const int n0 = (ccol * cn + nc2) * BN;

  const int nks = K >> 5;
  const int srow = tid >> 2;
  const int kq8 = (tid & 3) * 8;
  const unsigned short* A_ = A + (long)m0 * lda;
  const unsigned short* A2_ = DUALA ? (A2 + (long)m0 * lda) : nullptr;
  const unsigned short* B_ = Bt + (long)n0 * ldb;

  auto stage = [&](int s) {
    const int slot = s & 3;
    const long k32 = (long)s * 32;
    const unsigned short* Ab;
    long akofs;
    if constexpr (DUALA) {
      const int khalf = K >> 1;
      const bool lo = k32 < khalf;
      Ab = lo ? A_ : A2_;
      akofs = (lo ? k32 : k32 - khalf) + kq8;
    } else {
      Ab = A_;
      akofs = k32 + kq8;
    }
    const long bkofs = k32 + kq8;
#pragma unroll
    for (int j = 0; j < BM / RPR; ++j)
      load_lds16(Ab + (long)(j * RPR + srow) * lda + akofs,
                 &As[slot * ASLOT + (j * THREADS + tid) * 8]);
#pragma unroll
    for (int j = 0; j < BN / RPR; ++j)
      load_lds16(B_ + (long)(j * RPR + srow) * ldb + bkofs,
                 &Bs[slot * BSLOT + (j * THREADS + tid) * 8]);
  };

  f32x4 acc[FM][FN] = {};

  stage(0);
  if (nks > 1) stage(1);
  if (nks > 2) stage(2);
  vm_gate<2 * LPS>();
  __builtin_amdgcn_sched_barrier(0);
  __builtin_amdgcn_s_barrier();

  for (int s = 0; s < nks; ++s) {
    const int slot = s & 3;
    const unsigned short* Ap = &As[slot * ASLOT] + (wr * FM * 16 + c) * 32 + g * 8;
    const unsigned short* Bp = &Bs[slot * BSLOT] + (wc * FN * 16 + c) * 32 + g * 8;
    bf16x8 fa[FM], fb[FN];
#pragma unroll
    for (int fm = 0; fm < FM; ++fm) fa[fm] = *(const bf16x8*)(Ap + fm * 512);
#pragma unroll
    for (int fn = 0; fn < FN; ++fn) fb[fn] = *(const bf16x8*)(Bp + fn * 512);
    if (s + 3 < nks) stage(s + 3);
    __builtin_amdgcn_s_setprio(1);
#pragma unroll
    for (int fm = 0; fm < FM; ++fm)
#pragma unroll
      for (int fn = 0; fn < FN; ++fn)
        acc[fm][fn] = __builtin_amdgcn_mfma_f32_16x16x32_bf16(fa[fm], fb[fn], acc[fm][fn], 0, 0, 0);
    __builtin_amdgcn_s_setprio(0);
    if (s + 1 == nks) break;
    if (s <= nks - 4)
      vm_gate<2 * LPS>();
    else if (s == nks - 3)
      vm_gate<LPS>();
    else
      vm_gate<0>();
    __builtin_amdgcn_sched_barrier(0);
    __builtin_amdgcn_s_barrier();
  }

#pragma unroll
  for (int fm = 0; fm < FM; ++fm) {
#pragma unroll
    for (int r = 0; r < 4; ++r) {
      const int row = m0 + wr * FM * 16 + fm * 16 + 4 * g + r;
#pragma unroll
      for (int fn = 0; fn < FN; ++fn) {
        const int col = n0 + wc * FN * 16 + fn * 16 + c;
        const long idx2 = (long)row * ldc + col;
        float v = acc[fm][fn][r];
        if constexpr (EPI == 0) {
          ((unsigned short*)Cout)[idx2] = f2bf(v);
        } else if constexpr (EPI == 1) {
          ((float*)Cout)[idx2] = v + ((const float*)aux)[idx2];
        } else {
          const float u = bf2f(((const unsigned short*)aux)[idx2]);
          const float sg = v / (1.0f + __expf(-v));
          ((unsigned short*)Cout)[idx2] = f2bf(sg * u);
        }
      }
    }
  }
}

// ---------------- RoPE tables -----------------------------------------------
__global__ void rope_tables_kernel(float* __restrict__ cost, float* __restrict__ sint) {
  const int idx = blockIdx.x * 256 + threadIdx.x;  // T*64
  const int t = idx >> 6, i = idx & 63;
  const float invf = powf(10000.0f, -(float)i * (1.0f / 64.0f));
  const float ang = (float)t * invf;
  cost[idx] = cosf(ang);
  sint[idx] = sinf(ang);
}

// ---------------- RoPE apply (vectorized 8-wide) on q,k of qkv(bf16) --------
__global__ __launch_bounds__(256) void rope_apply_kernel(
    unsigned short* __restrict__ qkv, const float* __restrict__ cost,
    const float* __restrict__ sint) {
  const long idx = (long)blockIdx.x * 256 + threadIdx.x;  // BT*16*2*8
  const int u = (int)(idx & 7);
  const int h = (int)((idx >> 3) & 15);
  const int qk = (int)((idx >> 7) & 1);
  const long row = idx >> 8;  // 0..BT-1
  const int t = (int)(row & (T_SEQ - 1));
  unsigned short* p = qkv + row * (3 * D_MODEL) + qk * D_MODEL + h * D_HEAD + u * 8;
  u16x8 lo = *(const u16x8*)p;
  u16x8 hi = *(const u16x8*)(p + 64);
  const float4 c0 = *(const float4*)(cost + t * 64 + u * 8);
  const float4 c1 = *(const float4*)(cost + t * 64 + u * 8 + 4);
  const float4 s0 = *(const float4*)(sint + t * 64 + u * 8);
  const float4 s1 = *(const float4*)(sint + t * 64 + u * 8 + 4);
  const float cv[8] = {c0.x, c0.y, c0.z, c0.w, c1.x, c1.y, c1.z, c1.w};
  const float sv[8] = {s0.x, s0.y, s0.z, s0.w, s1.x, s1.y, s1.z, s1.w};
  u16x8 ro, rh;
#pragma unroll
  for (int j = 0; j < 8; ++j) {
    const float a = bf2f(lo[j]);
    const float b = bf2f(hi[j]);
    ro[j] = f2bf(a * cv[j] - b * sv[j]);
    rh[j] = f2bf(b * cv[j] + a * sv[j]);
  }
  *(u16x8*)p = ro;
  *(u16x8*)(p + 64) = rh;
}

// ---------------- V transpose (vectorized): qkv v -> vt [B,H,128,T] ---------
__global__ __launch_bounds__(256) void vtrans_kernel(
    const unsigned short* __restrict__ qkv, unsigned short* __restrict__ vt) {
  __shared__ unsigned short tile[64][68];
  const int tx = threadIdx.x, ty = threadIdx.y;  // [0,16)
  const int t0 = blockIdx.x * 64, d0 = blockIdx.y * 64;
  const int bh = blockIdx.z;  // b*16+h
  const int b = bh >> 4, h = bh & 15;
#pragma unroll
  for (int i = 0; i < 4; ++i) {
    const ushort4 v = *(const ushort4*)(
        qkv + (long)(b * T_SEQ + t0 + ty + 16 * i) * (3 * D_MODEL) + 2 * D_MODEL +
        h * D_HEAD + d0 + tx * 4);
    unsigned short* tr = &tile[ty + 16 * i][tx * 4];
    tr[0] = v.x; tr[1] = v.y; tr[2] = v.z; tr[3] = v.w;
  }
  __syncthreads();
#pragma unroll
  for (int i = 0; i < 4; ++i) {
    const int dd = ty + 16 * i;
    ushort4 o;
    o.x = tile[tx * 4 + 0][dd];
    o.y = tile[tx * 4 + 1][dd];
    o.z = tile[tx * 4 + 2][dd];
    o.w = tile[tx * 4 + 3][dd];
    *(ushort4*)(vt + ((long)bh * D_HEAD + d0 + dd) * T_SEQ + t0 + tx * 4) = o;
  }
}

// ---------------- Flash attention (causal), swapped-QK^T --------------------
__global__ __launch_bounds__(256) void attn_kernel(
    const unsigned short* __restrict__ qkv, const unsigned short* __restrict__ vt,
    unsigned short* __restrict__ ctx) {
  __shared__ unsigned short Ks[2][64 * 128];
  __shared__ unsigned short Vs[2][128 * 64];
  const int h = blockIdx.y, b = blockIdx.z;
  const int tid = threadIdx.x;
  const int w = tid >> 6, lane = tid & 63, g = lane >> 4, c = lane & 15;
  const float scale = 0.08838834764831845f;  // 128^-0.5
  const int srcA = (2 * (g & 1)) * 16 + c;
  const int srcB = srcA + 16;
  const bool hi = (g >> 1) != 0;
  const int bh = b * N_HEADS + h;

  const int ssk = (tid & 15) ^ ((tid >> 4) & 7);
  const int ssv = (tid & 7) ^ ((tid >> 3) & 7);
  const unsigned short* Kg = qkv + (long)b * T_SEQ * 3 * D_MODEL + D_MODEL + (long)h * D_HEAD;
  const unsigned short* Vg = vt + (long)bh * D_HEAD * T_SEQ;

  auto stage = [&](int kv0, int bufi) {
#pragma unroll
    for (int i = 0; i < 4; ++i) {
      const int rowk = i * 16 + (tid >> 4);
      load_lds16(Kg + (long)(kv0 + rowk) * (3 * D_MODEL) + ssk * 8,
                 &Ks[bufi][(i * 256 + tid) * 8]);
    }
#pragma unroll
    for (int i = 0; i < 4; ++i) {
      const int rowv = i * 32 + (tid >> 3);
      load_lds16(Vg + (long)rowv * T_SEQ + kv0 + ssv * 8,
                 &Vs[bufi][(i * 256 + tid) * 8]);
    }
  };

  const int cs7 = c & 7;

  for (int pass = 0; pass < 2; ++pass) {
    const int qt = pass ? (NT - 1 - blockIdx.x) : blockIdx.x;
    const int q = qt * 64 + w * 16 + c;

    bf16x8 fq[4];
    const long rowQ = (long)(b * T_SEQ + q) * (3 * D_MODEL) + h * D_HEAD;
#pragma unroll
    for (int ks = 0; ks < 4; ++ks)
      fq[ks] = *(const bf16x8*)(qkv + rowQ + ks * 32 + g * 8);

    f32x4 o[8] = {};
    float mrun = -INFINITY, ell = 0.0f;

    stage(0, 0);
    asm volatile("s_waitcnt vmcnt(0)" ::: "memory");
    __syncthreads();
    int buf = 0;

    for (int kt = 0; kt <= qt; ++kt) {
      const int kv0 = kt * 64;
      if (kt < qt) stage(kv0 + 64, buf ^ 1);

      f32x4 s[4] = {};
      __builtin_amdgcn_s_setprio(1);
#pragma unroll
      for (int fm = 0; fm < 4; ++fm) {
        const unsigned short* kr = &Ks[buf][(fm * 16 + c) * 128];
#pragma unroll
        for (int ks = 0; ks < 4; ++ks) {
          bf16x8 ak = *(const bf16x8*)(kr + ((ks * 4 + g) ^ cs7) * 8);
          s[fm] = __builtin_amdgcn_mfma_f32_16x16x32_bf16(ak, fq[ks], s[fm], 0, 0, 0);
        }
      }
      __builtin_amdgcn_s_setprio(0);
      float pmax = -INFINITY;
      const bool diag = (kt == qt);
#pragma unroll
      for (int fm = 0; fm < 4; ++fm)
#pragma unroll
        for (int r = 0; r < 4; ++r) {
          float sv = s[fm][r] * scale;
          if (diag) {
            const int kp = kv0 + fm * 16 + 4 * g + r;
            if (kp > q) sv = -INFINITY;
          }
          s[fm][r] = sv;
          pmax = fmaxf(pmax, sv);
        }
      pmax = fmaxf(pmax, __shfl_xor(pmax, 16));
      pmax = fmaxf(pmax, __shfl_xor(pmax, 32));
      const float mnew = fmaxf(mrun, pmax);
      const float resc = __expf(mrun - mnew);
      mrun = mnew;
      float rowsum = 0.0f;
#pragma unroll
      for (int fm = 0; fm < 4; ++fm)
#pragma unroll
        for (int r = 0; r < 4; ++r) {
          const float p = __expf(s[fm][r] - mnew);
          s[fm][r] = p;
          rowsum += p;
        }
      rowsum += __shfl_xor(rowsum, 16);
      rowsum += __shfl_xor(rowsum, 32);
      ell = ell * resc + rowsum;
#pragma unroll
      for (int fm = 0; fm < 8; ++fm) o[fm] *= resc;

      bf16x8 pb[2];
#pragma unroll
      for (int k2 = 0; k2 < 2; ++k2) {
        float va[4], vb[4];
#pragma unroll
        for (int r = 0; r < 4; ++r) {
          const float t0 = __shfl(s[k2 * 2][r], srcA);
          const float t1 = __shfl(s[k2 * 2 + 1][r], srcA);
          va[r] = hi ? t1 : t0;
          const float u0 = __shfl(s[k2 * 2][r], srcB);
          const float u1 = __shfl(s[k2 * 2 + 1][r], srcB);
          vb[r] = hi ? u1 : u0;
        }
        bf16x8 pv;
        pv[0] = (__bf16)va[0]; pv[1] = (__bf16)va[1];
        pv[2] = (__bf16)va[2]; pv[3] = (__bf16)va[3];
        pv[4] = (__bf16)vb[0]; pv[5] = (__bf16)vb[1];
        pv[6] = (__bf16)vb[2]; pv[7] = (__bf16)vb[3];
        pb[k2] = pv;
      }
      __builtin_amdgcn_s_setprio(1);
#pragma unroll
      for (int fm = 0; fm < 8; ++fm) {
        const unsigned short* vr = &Vs[buf][(fm * 16 + c) * 64];
#pragma unroll
        for (int k2 = 0; k2 < 2; ++k2) {
          bf16x8 av = *(const bf16x8*)(vr + ((k2 * 4 + g) ^ cs7) * 8);
          o[fm] = __builtin_amdgcn_mfma_f32_16x16x32_bf16(av, pb[k2], o[fm], 0, 0, 0);
        }
      }
      __builtin_amdgcn_s_setprio(0);
      asm volatile("s_waitcnt vmcnt(0)" ::: "memory");
      __syncthreads();
      buf ^= 1;
    }

    const float inv = 1.0f / ell;
    unsigned short* outp = ctx + (long)(b * T_SEQ + q) * D_MODEL + h * D_HEAD;
#pragma unroll
    for (int fm = 0; fm < 8; ++fm) {
      ushort4 pk;
      pk.x = f2bf(o[fm][0] * inv);
      pk.y = f2bf(o[fm][1] * inv);
      pk.z = f2bf(o[fm][2] * inv);
      pk.w = f2bf(o[fm][3] * inv);
      *(ushort4*)(outp + fm * 16 + 4 * g) = pk;
    }
  }
}

// ---------------------------------------------------------------------------
extern "C" void kernel_launch(void* const* d_in, const int* in_sizes, int n_in,
                              void* d_out, int out_size, void* d_ws, size_t ws_size,
                              hipStream_t stream) {
  const float* x = (const float*)d_in[0];
  const float* w_qkv = (const float*)d_in[1];
  const float* w_out = (const float*)d_in[2];
  const float* g1 = (const float*)d_in[3];
  const float* g2 = (const float*)d_in[4];
  const float* w_g = (const float*)d_in[5];
  const float* w_u = (const float*)d_in[6];
  const float* w_o = (const float*)d_in[7];
  float* out = (float*)d_out;

  char* ws = (char*)d_ws;
  size_t off = 0;
  auto take = [&](size_t bytes) {
    char* p = ws + off;
    off += (bytes + 255) & ~(size_t)255;
    return p;
  };

  char* Wreg = take((size_t)3 * D_FF * D_MODEL * 2);  // 100.66 MB
  unsigned short* wTqkv = (unsigned short*)Wreg;
  unsigned short* wTout = (unsigned short*)(Wreg + (size_t)3 * D_MODEL * D_MODEL * 2);
  unsigned short* wTg = (unsigned short*)Wreg;
  unsigned short* wTu = (unsigned short*)(Wreg + (size_t)D_FF * D_MODEL * 2);
  unsigned short* wTo = (unsigned short*)(Wreg + (size_t)2 * D_FF * D_MODEL * 2);

  const size_t qkv_b = (size_t)BT * 3 * D_MODEL * 2;
  const size_t vt_b = (size_t)B_SZ * N_HEADS * D_HEAD * T_SEQ * 2;
  const size_t ctx_b = (size_t)BT * D_MODEL * 2;
  char* AR = take(qkv_b + vt_b + ctx_b);  // 83.9 MB
  unsigned short* qkvb = (unsigned short*)AR;
  unsigned short* vtb = (unsigned short*)(AR + qkv_b);
  unsigned short* ctxb = (unsigned short*)(AR + qkv_b + vt_b);
  unsigned short* gbuf0 = (unsigned short*)AR;                                   // 33.6 MB
  unsigned short* gbuf1 = (unsigned short*)(AR + (size_t)BT * (D_FF / 2) * 2);   // 33.6 MB

  float* x1 = (float*)take((size_t)BT * D_MODEL * 4);
  unsigned short* hb = (unsigned short*)take((size_t)BT * D_MODEL * 2);
  float* cost = (float*)take((size_t)T_SEQ * 64 * 4);
  float* sint = (float*)take((size_t)T_SEQ * 64 * 4);

  const dim3 tb(16, 16);

  // ---- phase A: attention ----
  transpose_cast_kernel<<<dim3(3 * D_MODEL / 64, D_MODEL / 64), tb, 0, stream>>>(w_qkv, wTqkv, D_MODEL, 3 * D_MODEL);
  transpose_cast_kernel<<<dim3(D_MODEL / 64, D_MODEL / 64), tb, 0, stream>>>(w_out, wTout, D_MODEL, D_MODEL);
  rope_tables_kernel<<<T_SEQ * 64 / 256, 256, 0, stream>>>(cost, sint);

  rmsnorm_cast_kernel<<<BT, 256, 0, stream>>>(x, g1, hb);
  // QKV: 256^2; nbm=16, nbn=24 -> 384 blocks, XCD rect 8x6
  gemm_ks_kernel<0, 2, 4, 8, 4><<<384, 512, 0, stream>>>(
      hb, wTqkv, qkvb, nullptr, nullptr, BT, 3 * D_MODEL, D_MODEL, D_MODEL, D_MODEL, 3 * D_MODEL, 8, 6);
  rope_apply_kernel<<<(BT * N_HEADS * 2 * 8) / 256, 256, 0, stream>>>(qkvb, cost, sint);
  vtrans_kernel<<<dim3(T_SEQ / 64, D_HEAD / 64, B_SZ * N_HEADS), tb, 0, stream>>>(qkvb, vtb);
  attn_kernel<<<dim3(NT / 2, N_HEADS, B_SZ), 256, 0, stream>>>(qkvb, vtb, ctxb);
  // out-proj: 256x128; 256 blocks, rect 8x4
  gemm_ks_kernel<1, 4, 2, 4, 4><<<256, 512, 0, stream>>>(
      ctxb, wTout, x1, x, nullptr, BT, D_MODEL, D_MODEL, D_MODEL, D_MODEL, D_MODEL, 8, 4);

  // ---- phase B: MLP ----
  transpose_cast_kernel<<<dim3(D_FF / 64, D_MODEL / 64), tb, 0, stream>>>(w_g, wTg, D_MODEL, D_FF);
  transpose_cast_kernel<<<dim3(D_FF / 64, D_MODEL / 64), tb, 0, stream>>>(w_u, wTu, D_MODEL, D_FF);
  transpose_cast_kernel<<<dim3(D_MODEL / 64, D_FF / 64), tb, 0, stream>>>(w_o, wTo, D_FF, D_MODEL);
  rmsnorm_cast_kernel<<<BT, 256, 0, stream>>>(x1, g2, hb);

  const int NH = D_FF / 2;  // 4096 ff-columns per half
  for (int half = 0; half < 2; ++half) {
    const unsigned short* wTu_h = wTu + (size_t)half * NH * D_MODEL;
    const unsigned short* wTg_h = wTg + (size_t)half * NH * D_MODEL;
    unsigned short* gb = half ? gbuf1 : gbuf0;
    // up half -> gb (raw u)
    gemm_ks_kernel<0, 2, 4, 8, 4><<<256, 512, 0, stream>>>(
        hb, wTu_h, gb, nullptr, nullptr, BT, NH, D_MODEL, D_MODEL, D_MODEL, NH, 4, 8);
    // gate half, in-place SwiGLU: gb <- silu(h@wTg) * gb
    gemm_ks_kernel<2, 2, 4, 8, 4><<<256, 512, 0, stream>>>(
        hb, wTg_h, gb, gb, nullptr, BT, NH, D_MODEL, D_MODEL, D_MODEL, NH, 4, 8);
  }
  // down: single K=8192 dispatch, A = gbuf0 (k<4096) / gbuf1 (k>=4096)
  gemm_ks_kernel<1, 4, 2, 4, 4, true><<<256, 512, 0, stream>>>(
      gbuf0, wTo, out, x1, gbuf1, BT, D_MODEL, D_FF, NH, D_FF, D_MODEL, 8, 4);
}